// Round 1
// baseline (9187.376 us; speedup 1.0000x reference)
//
#include <hip/hip_runtime.h>
#include <hip/hip_bf16.h>
#include <math.h>

// Problem constants (reference: B=4, S=2048, D=1024, fp32).
#define ATT_B 4
#define ATT_S 2048
#define ATT_D 1024

// ---------------------------------------------------------------------------
// Kernel 1: fp32 tiled GEMM  C[M,N] = A[M,K] @ W[K,N]   (row-major all)
// BM=BN=64, BK=16, 256 threads, 4x4 microtile per thread.
// ---------------------------------------------------------------------------
#define TILE_M 64
#define TILE_N 64
#define TILE_K 16

__global__ __launch_bounds__(256)
void gemm_f32(const float* __restrict__ A, const float* __restrict__ W,
              float* __restrict__ C, int M, int N, int K) {
  __shared__ float As[TILE_K][TILE_M + 4];  // +4 pad: keeps 16B align, kills conflicts
  __shared__ float Bs[TILE_K][TILE_N];

  const int tid  = threadIdx.x;
  const int row0 = blockIdx.y * TILE_M;
  const int col0 = blockIdx.x * TILE_N;
  const int tx   = tid & 15;   // 0..15  -> N direction
  const int ty   = tid >> 4;   // 0..15  -> M direction

  float acc[4][4] = {};

  for (int k0 = 0; k0 < K; k0 += TILE_K) {
    // A tile: 64 rows x 16 cols (transposed into As[k][m])
#pragma unroll
    for (int i = 0; i < 4; ++i) {
      int lin = tid + i * 256;          // 0..1023
      int r = lin >> 4;                 // 0..63
      int c = lin & 15;                 // 0..15
      As[c][r] = A[(size_t)(row0 + r) * K + (k0 + c)];
    }
    // W tile: 16 rows x 64 cols
#pragma unroll
    for (int i = 0; i < 4; ++i) {
      int lin = tid + i * 256;
      int r = lin >> 6;                 // 0..15
      int c = lin & 63;                 // 0..63
      Bs[r][c] = W[(size_t)(k0 + r) * N + (col0 + c)];
    }
    __syncthreads();

#pragma unroll
    for (int k = 0; k < TILE_K; ++k) {
      const float4 av = *reinterpret_cast<const float4*>(&As[k][ty * 4]);
      const float4 bv = *reinterpret_cast<const float4*>(&Bs[k][tx * 4]);
      const float a[4] = {av.x, av.y, av.z, av.w};
      const float b[4] = {bv.x, bv.y, bv.z, bv.w};
#pragma unroll
      for (int i = 0; i < 4; ++i)
#pragma unroll
        for (int j = 0; j < 4; ++j)
          acc[i][j] += a[i] * b[j];
    }
    __syncthreads();
  }

#pragma unroll
  for (int i = 0; i < 4; ++i) {
    const size_t r = (size_t)(row0 + ty * 4 + i);
    float4 out = {acc[i][0], acc[i][1], acc[i][2], acc[i][3]};
    *reinterpret_cast<float4*>(&C[r * N + col0 + tx * 4]) = out;
  }
}

// ---------------------------------------------------------------------------
// Kernel 2: fp32 flash attention (no 1/sqrt(d) scaling, per reference).
// Block = (batch b, 16 query rows). 256 threads.
// Q tile staged in LDS (16 x 1024 fp32 = 64 KB). Online softmax (m, l).
// Each thread owns cols [4*tid, 4*tid+3] of all 16 rows: acc[16][4].
// ---------------------------------------------------------------------------
#define BR 16
#define BC 16

__global__ __launch_bounds__(256)
void attn_f32(const float* __restrict__ Q, const float* __restrict__ K,
              const float* __restrict__ V, float* __restrict__ O) {
  const int S = ATT_S, D = ATT_D;
  const int b  = blockIdx.y;
  const int q0 = blockIdx.x * BR;
  const int tid = threadIdx.x;
  const size_t base = (size_t)b * S * D;

  const float* Qb = Q + base;
  const float* Kb = K + base;
  const float* Vb = V + base;
  float*       Ob = O + base;

  __shared__ float Qs[BR][ATT_D];          // 64 KB
  __shared__ float Ps[BR][BC];             // scores -> probs
  __shared__ float Ms[BR], Ls[BR], Fs[BR];

  // ---- stage Q tile (float4, fully coalesced: 4096 float4s / 256 threads) --
  {
    float4* qs4 = reinterpret_cast<float4*>(&Qs[0][0]);
    const float4* qg4 = reinterpret_cast<const float4*>(Qb + (size_t)q0 * D);
#pragma unroll
    for (int i = 0; i < 16; ++i) {
      int lin = tid + i * 256;
      qs4[lin] = qg4[lin];
    }
  }
  if (tid < BR) { Ms[tid] = -1e30f; Ls[tid] = 0.f; }

  float acc[BR][4];
#pragma unroll
  for (int i = 0; i < BR; ++i) {
    acc[i][0] = 0.f; acc[i][1] = 0.f; acc[i][2] = 0.f; acc[i][3] = 0.f;
  }
  __syncthreads();

  const int si = tid >> 4;   // 0..15 : query row for score phase
  const int sj = tid & 15;   // 0..15 : key row for score phase
  const int c0 = tid * 4;    // output column slice

  for (int k0 = 0; k0 < S; k0 += BC) {
    // ---- scores: thread (si,sj) computes Q[si] . K[k0+sj] over D ----------
    {
      const float4* kr = reinterpret_cast<const float4*>(Kb + (size_t)(k0 + sj) * D);
      const float4* qr = reinterpret_cast<const float4*>(&Qs[si][0]);
      float s0 = 0.f, s1 = 0.f, s2 = 0.f, s3 = 0.f;
#pragma unroll 4
      for (int t = 0; t < ATT_D / 4; ++t) {
        const float4 qv = qr[t];
        const float4 kv = kr[t];
        s0 += qv.x * kv.x;
        s1 += qv.y * kv.y;
        s2 += qv.z * kv.z;
        s3 += qv.w * kv.w;
      }
      Ps[si][sj] = (s0 + s1) + (s2 + s3);
    }
    __syncthreads();

    // ---- online softmax update (one thread per row) -----------------------
    if (tid < BR) {
      const float m_old = Ms[tid];
      float mx = m_old;
#pragma unroll
      for (int j = 0; j < BC; ++j) mx = fmaxf(mx, Ps[tid][j]);
      const float f = __expf(m_old - mx);
      float sum = 0.f;
#pragma unroll
      for (int j = 0; j < BC; ++j) {
        const float p = __expf(Ps[tid][j] - mx);
        Ps[tid][j] = p;
        sum += p;
      }
      Fs[tid] = f;
      Ms[tid] = mx;
      Ls[tid] = Ls[tid] * f + sum;
    }
    __syncthreads();

    // ---- rescale accumulators ---------------------------------------------
#pragma unroll
    for (int i = 0; i < BR; ++i) {
      const float f = Fs[i];
      acc[i][0] *= f; acc[i][1] *= f; acc[i][2] *= f; acc[i][3] *= f;
    }

    // ---- PV: acc[i][:] += P[i][j] * V[k0+j][c0..c0+3] ---------------------
#pragma unroll
    for (int j4 = 0; j4 < BC / 4; ++j4) {
      const float4 v0 = *reinterpret_cast<const float4*>(Vb + (size_t)(k0 + j4 * 4 + 0) * D + c0);
      const float4 v1 = *reinterpret_cast<const float4*>(Vb + (size_t)(k0 + j4 * 4 + 1) * D + c0);
      const float4 v2 = *reinterpret_cast<const float4*>(Vb + (size_t)(k0 + j4 * 4 + 2) * D + c0);
      const float4 v3 = *reinterpret_cast<const float4*>(Vb + (size_t)(k0 + j4 * 4 + 3) * D + c0);
#pragma unroll
      for (int i = 0; i < BR; ++i) {
        const float4 p = *reinterpret_cast<const float4*>(&Ps[i][j4 * 4]);
        acc[i][0] += p.x * v0.x + p.y * v1.x + p.z * v2.x + p.w * v3.x;
        acc[i][1] += p.x * v0.y + p.y * v1.y + p.z * v2.y + p.w * v3.y;
        acc[i][2] += p.x * v0.z + p.y * v1.z + p.z * v2.z + p.w * v3.z;
        acc[i][3] += p.x * v0.w + p.y * v1.w + p.z * v2.w + p.w * v3.w;
      }
    }
    __syncthreads();  // protect Ps/Ms/Ls for next tile
  }

  // ---- epilogue: divide by l, write out (coalesced float4) -----------------
#pragma unroll
  for (int i = 0; i < BR; ++i) {
    const float inv = 1.f / Ls[i];
    float4 out = {acc[i][0] * inv, acc[i][1] * inv, acc[i][2] * inv, acc[i][3] * inv};
    *reinterpret_cast<float4*>(Ob + (size_t)(q0 + i) * D + c0) = out;
  }
}

// ---------------------------------------------------------------------------
extern "C" void kernel_launch(void* const* d_in, const int* in_sizes, int n_in,
                              void* d_out, int out_size, void* d_ws, size_t ws_size,
                              hipStream_t stream) {
  const float* x  = (const float*)d_in[0];
  const float* Wq = (const float*)d_in[1];
  const float* Wk = (const float*)d_in[2];
  const float* Wv = (const float*)d_in[3];
  float* out = (float*)d_out;

  const int M = ATT_B * ATT_S;       // 8192
  const int D = ATT_D;               // 1024
  const size_t n = (size_t)M * D;    // 8.39M floats

  float* Qw = (float*)d_ws;          // 32 MB
  float* Kw = Qw + n;                // 32 MB
  float* Vw = Kw + n;                // 32 MB  (needs ws_size >= 96 MB)

  dim3 gg(D / TILE_N, M / TILE_M);   // (16, 128)
  gemm_f32<<<gg, 256, 0, stream>>>(x, Wq, Qw, M, D, D);
  gemm_f32<<<gg, 256, 0, stream>>>(x, Wk, Kw, M, D, D);
  gemm_f32<<<gg, 256, 0, stream>>>(x, Wv, Vw, M, D, D);

  dim3 ga(ATT_S / BR, ATT_B);        // (128, 4)
  attn_f32<<<ga, 256, 0, stream>>>(Qw, Kw, Vw, out);
}

// Round 2
// 431.456 us; speedup vs baseline: 21.2939x; 21.2939x over previous
//
#include <hip/hip_runtime.h>
#include <hip/hip_bf16.h>

#define ATT_B 4
#define ATT_S 2048
#define ATT_D 1024

#define BM 128
#define BN 128
#define BK 32

typedef __attribute__((ext_vector_type(8))) short bf16x8;   // MFMA A/B frag (8 bf16)
typedef __attribute__((ext_vector_type(4))) float f32x4;    // MFMA C/D frag

// round-to-nearest-even f32 -> bf16 bits
__device__ inline unsigned short f2bf_rne(float f) {
  unsigned u = __float_as_uint(f);
  u += 0x7FFFu + ((u >> 16) & 1u);
  return (unsigned short)(u >> 16);
}

// async global->LDS, 16B per lane. lds ptr must be wave-uniform.
__device__ inline void gll16(const void* g, void* l) {
  __builtin_amdgcn_global_load_lds(
      (const __attribute__((address_space(1))) void*)g,
      (__attribute__((address_space(3))) void*)l, 16, 0, 0);
}

// ---------------------------------------------------------------------------
// Universal GEMM: C[M,N] = A[M,K] * BT[N,K]^T  (both operands K-major rows)
// NT: 1 = plain bf16 (hi only), 3 = split-bf16 3-term (hi*hi + hi*lo + lo*hi)
// AMODE: 0 = A is bf16 hi(/lo) arrays (global_load_lds staging)
//        1 = A is fp32, converted to hi/lo during reg-staging
// OMODE: 0 = fp32 C, 1 = bf16 hi/lo pair C (C0,C1), 2 = bf16 transposed V^T
// ---------------------------------------------------------------------------
template<int NT, int AMODE, int OMODE>
__global__ __launch_bounds__(256, 2)
void gemm_bt(const void* __restrict__ Apv, const void* __restrict__ Alv,
             const unsigned short* __restrict__ Bh,
             const unsigned short* __restrict__ Bl,
             void* __restrict__ C0, void* __restrict__ C1,
             int K, int pitchA, int pitchB, int pitchC, int mtiles_pb,
             size_t Abstride, size_t Bbstride, size_t Cbstride)
{
  __shared__ unsigned short sAh[BM * BK];
  __shared__ unsigned short sBh[BN * BK];
  __shared__ unsigned short sAl[(NT == 3) ? BM * BK : 8];
  __shared__ unsigned short sBl[(NT == 3) ? BN * BK : 8];

  const int tid  = threadIdx.x;
  const int wave = tid >> 6;
  const int lane = tid & 63;
  const int l16  = lane & 15;
  const int lh   = lane >> 4;      // 0..3
  const int wm   = wave >> 1;      // wave tile row (0..1)
  const int wn   = wave & 1;       // wave tile col (0..1)

  const int bt   = blockIdx.y / mtiles_pb;   // batch index
  const int ml   = blockIdx.y % mtiles_pb;   // m-tile within batch
  const int row0 = ml * BM;
  const int col0 = blockIdx.x * BN;

  const unsigned short* Bhb = Bh + (size_t)bt * Bbstride;
  const unsigned short* Blb = (NT == 3) ? (Bl + (size_t)bt * Bbstride) : (const unsigned short*)nullptr;

  const unsigned short* Ahb = nullptr;
  const unsigned short* Alb = nullptr;
  const float*          Af  = nullptr;
  if (AMODE == 0) {
    Ahb = (const unsigned short*)Apv + (size_t)bt * Abstride;
    if (NT == 3) Alb = (const unsigned short*)Alv + (size_t)bt * Abstride;
  } else {
    Af = (const float*)Apv + (size_t)bt * Abstride;
  }

  f32x4 acc[4][4] = {};

  for (int k0 = 0; k0 < K; k0 += BK) {
    // ---- stage B tile (BN x BK bf16 = 8 KB) via global_load_lds ----------
#pragma unroll
    for (int j = 0; j < 2; ++j) {
      const int off = tid * 16 + j * 4096;
      const int r   = off >> 6;       // n-row 0..127
      const int kb  = off & 63;       // byte in row
      const char* g = (const char*)Bhb + ((size_t)(col0 + r) * pitchB + k0) * 2 + kb;
      char* l = (char*)sBh + (wave << 10) + j * 4096;
      gll16(g, l);
    }
    if (NT == 3) {
#pragma unroll
      for (int j = 0; j < 2; ++j) {
        const int off = tid * 16 + j * 4096;
        const int r   = off >> 6;
        const int kb  = off & 63;
        const char* g = (const char*)Blb + ((size_t)(col0 + r) * pitchB + k0) * 2 + kb;
        char* l = (char*)sBl + (wave << 10) + j * 4096;
        gll16(g, l);
      }
    }

    // ---- stage A tile ----------------------------------------------------
    if (AMODE == 0) {
#pragma unroll
      for (int j = 0; j < 2; ++j) {
        const int off = tid * 16 + j * 4096;
        const int r   = off >> 6;
        const int kb  = off & 63;
        const char* g = (const char*)Ahb + ((size_t)(row0 + r) * pitchA + k0) * 2 + kb;
        char* l = (char*)sAh + (wave << 10) + j * 4096;
        gll16(g, l);
      }
      if (NT == 3) {
#pragma unroll
        for (int j = 0; j < 2; ++j) {
          const int off = tid * 16 + j * 4096;
          const int r   = off >> 6;
          const int kb  = off & 63;
          const char* g = (const char*)Alb + ((size_t)(row0 + r) * pitchA + k0) * 2 + kb;
          char* l = (char*)sAl + (wave << 10) + j * 4096;
          gll16(g, l);
        }
      }
    } else {
      // fp32 A: reg-stage + convert to hi/lo bf16
#pragma unroll
      for (int j = 0; j < 4; ++j) {
        const int lin4 = tid + j * 256;     // float4 index in 128x32 tile
        const int r    = lin4 >> 3;         // row
        const int c4   = lin4 & 7;          // float4 within row
        const float4 v = *(const float4*)(Af + (size_t)(row0 + r) * pitchA + k0 + c4 * 4);
        const unsigned ux = __float_as_uint(v.x), uy = __float_as_uint(v.y);
        const unsigned uz = __float_as_uint(v.z), uw = __float_as_uint(v.w);
        ushort4 hi;
        hi.x = (unsigned short)(ux >> 16); hi.y = (unsigned short)(uy >> 16);
        hi.z = (unsigned short)(uz >> 16); hi.w = (unsigned short)(uw >> 16);
        *(ushort4*)&sAh[r * BK + c4 * 4] = hi;
        if (NT == 3) {
          ushort4 lo;
          lo.x = f2bf_rne(v.x - __uint_as_float(ux & 0xFFFF0000u));
          lo.y = f2bf_rne(v.y - __uint_as_float(uy & 0xFFFF0000u));
          lo.z = f2bf_rne(v.z - __uint_as_float(uz & 0xFFFF0000u));
          lo.w = f2bf_rne(v.w - __uint_as_float(uw & 0xFFFF0000u));
          *(ushort4*)&sAl[r * BK + c4 * 4] = lo;
        }
      }
    }
    __syncthreads();

    // ---- fragment loads (contiguous 16B per lane) + MFMA -----------------
    bf16x8 ah[4], bh4[4], al[4], bl4[4];
#pragma unroll
    for (int t = 0; t < 4; ++t) {
      ah[t]  = *(const bf16x8*)&sAh[(wm * 64 + t * 16 + l16) * BK + lh * 8];
      bh4[t] = *(const bf16x8*)&sBh[(wn * 64 + t * 16 + l16) * BK + lh * 8];
      if (NT == 3) {
        al[t]  = *(const bf16x8*)&sAl[(wm * 64 + t * 16 + l16) * BK + lh * 8];
        bl4[t] = *(const bf16x8*)&sBl[(wn * 64 + t * 16 + l16) * BK + lh * 8];
      }
    }
#pragma unroll
    for (int i = 0; i < 4; ++i)
#pragma unroll
      for (int j = 0; j < 4; ++j) {
        f32x4 c = acc[i][j];
        if (NT == 3) {
          c = __builtin_amdgcn_mfma_f32_16x16x32_bf16(al[i], bh4[j], c, 0, 0, 0);
          c = __builtin_amdgcn_mfma_f32_16x16x32_bf16(ah[i], bl4[j], c, 0, 0, 0);
        }
        c = __builtin_amdgcn_mfma_f32_16x16x32_bf16(ah[i], bh4[j], c, 0, 0, 0);
        acc[i][j] = c;
      }
    __syncthreads();
  }

  // ---- epilogue: C[row=(lh*4+r), col=l16] per 16x16 frag (m89-verified) ---
#pragma unroll
  for (int i = 0; i < 4; ++i) {
    const int mBase = row0 + wm * 64 + i * 16 + lh * 4;
#pragma unroll
    for (int j = 0; j < 4; ++j) {
      const int n = col0 + wn * 64 + j * 16 + l16;
      if (OMODE == 0) {
        float* C = (float*)C0 + (size_t)bt * Cbstride;
#pragma unroll
        for (int r = 0; r < 4; ++r)
          C[(size_t)(mBase + r) * pitchC + n] = acc[i][j][r];
      } else if (OMODE == 1) {
        unsigned short* Ch = (unsigned short*)C0;
        unsigned short* Cl = (unsigned short*)C1;
#pragma unroll
        for (int r = 0; r < 4; ++r) {
          const float f = acc[i][j][r];
          const unsigned u = __float_as_uint(f);
          Ch[(size_t)(mBase + r) * pitchC + n] = (unsigned short)(u >> 16);
          Cl[(size_t)(mBase + r) * pitchC + n] =
              f2bf_rne(f - __uint_as_float(u & 0xFFFF0000u));
        }
      } else {
        // V^T store: Vt[batch][n][srow], batch from global m row
        unsigned short* Vt = (unsigned short*)C0;
        const int b2 = mBase >> 11;          // /2048
        const int sr = mBase & 2047;
        ushort4 o;
        o.x = f2bf_rne(acc[i][j][0]); o.y = f2bf_rne(acc[i][j][1]);
        o.z = f2bf_rne(acc[i][j][2]); o.w = f2bf_rne(acc[i][j][3]);
        *(ushort4*)&Vt[(size_t)b2 * (1024u * 2048u) + (size_t)n * 2048 + sr] = o;
      }
    }
  }
}

// ---------------------------------------------------------------------------
// W [1024][1024] fp32 -> Wh/Wl bf16 [n][k] (transposed, split)
// ---------------------------------------------------------------------------
__global__ __launch_bounds__(256)
void wsplit(const float* __restrict__ W, unsigned short* __restrict__ Wh,
            unsigned short* __restrict__ Wl) {
  __shared__ float t[32][33];
  const int k0 = blockIdx.x * 32;
  const int n0 = blockIdx.y * 32;
  const int tx = threadIdx.x & 31;
  const int ty = threadIdx.x >> 5;   // 0..7
#pragma unroll
  for (int i = 0; i < 32; i += 8)
    t[ty + i][tx] = W[(size_t)(k0 + ty + i) * 1024 + (n0 + tx)];
  __syncthreads();
#pragma unroll
  for (int i = 0; i < 32; i += 8) {
    const float f = t[tx][ty + i];   // = W[k0+tx][n0+ty+i]
    const unsigned u = __float_as_uint(f);
    Wh[(size_t)(n0 + ty + i) * 1024 + (k0 + tx)] = (unsigned short)(u >> 16);
    Wl[(size_t)(n0 + ty + i) * 1024 + (k0 + tx)] =
        f2bf_rne(f - __uint_as_float(u & 0xFFFF0000u));
  }
}

// ---------------------------------------------------------------------------
// Row softmax, in place: reads 2048 fp32 scores, writes 2048 bf16 P over the
// start of the same row. One wave per row, 4 rows per block.
// ---------------------------------------------------------------------------
__global__ __launch_bounds__(256)
void softmax_inplace(float* __restrict__ S) {
  const int wave = threadIdx.x >> 6;
  const int lane = threadIdx.x & 63;
  float* rp = S + ((size_t)blockIdx.x * 4 + wave) * 2048;

  float4 v[8];
#pragma unroll
  for (int i = 0; i < 8; ++i) v[i] = *(const float4*)&rp[lane * 4 + i * 256];

  float m = -1e30f;
#pragma unroll
  for (int i = 0; i < 8; ++i)
    m = fmaxf(m, fmaxf(fmaxf(v[i].x, v[i].y), fmaxf(v[i].z, v[i].w)));
#pragma unroll
  for (int s = 32; s; s >>= 1) m = fmaxf(m, __shfl_xor(m, s));

  float sum = 0.f;
#pragma unroll
  for (int i = 0; i < 8; ++i) {
    v[i].x = __expf(v[i].x - m); v[i].y = __expf(v[i].y - m);
    v[i].z = __expf(v[i].z - m); v[i].w = __expf(v[i].w - m);
    sum += (v[i].x + v[i].y) + (v[i].z + v[i].w);
  }
#pragma unroll
  for (int s = 32; s; s >>= 1) sum += __shfl_xor(sum, s);
  const float inv = 1.0f / sum;

  unsigned short* pp = (unsigned short*)rp;
#pragma unroll
  for (int i = 0; i < 8; ++i) {
    ushort4 o;
    o.x = f2bf_rne(v[i].x * inv); o.y = f2bf_rne(v[i].y * inv);
    o.z = f2bf_rne(v[i].z * inv); o.w = f2bf_rne(v[i].w * inv);
    *(ushort4*)&pp[lane * 4 + i * 256] = o;
  }
}

// ---------------------------------------------------------------------------
extern "C" void kernel_launch(void* const* d_in, const int* in_sizes, int n_in,
                              void* d_out, int out_size, void* d_ws, size_t ws_size,
                              hipStream_t stream) {
  const float* x  = (const float*)d_in[0];
  const float* Wq = (const float*)d_in[1];
  const float* Wk = (const float*)d_in[2];
  const float* Wv = (const float*)d_in[3];
  float* out = (float*)d_out;

  char* ws = (char*)d_ws;
  const size_t MB = 1024 * 1024;
  unsigned short* Qh = (unsigned short*)(ws + 0 * MB);
  unsigned short* Ql = (unsigned short*)(ws + 16 * MB);
  unsigned short* Kh = (unsigned short*)(ws + 32 * MB);
  unsigned short* Kl = (unsigned short*)(ws + 48 * MB);
  unsigned short* Vt = (unsigned short*)(ws + 64 * MB);
  char* R = ws + 80 * MB;               // transient: W splits, then scores
  unsigned short* Wqh = (unsigned short*)(R + 0 * MB);
  unsigned short* Wql = (unsigned short*)(R + 2 * MB);
  unsigned short* Wkh = (unsigned short*)(R + 4 * MB);
  unsigned short* Wkl = (unsigned short*)(R + 6 * MB);
  unsigned short* Wvh = (unsigned short*)(R + 8 * MB);
  unsigned short* Wvl = (unsigned short*)(R + 10 * MB);
  float* Sbuf = (float*)R;

  // stripe height: largest h with scores buffer B*h*S*4 fitting after 80MB
  const size_t avail = (ws_size > 80 * MB) ? (ws_size - 80 * MB) : 0;
  int h = 128;
  const int cands[4] = {2048, 1024, 512, 256};
  for (int c = 0; c < 4; ++c) {
    if ((size_t)4 * cands[c] * 2048 * 4 <= avail) { h = cands[c]; break; }
  }

  // ---- W preprocessing ----------------------------------------------------
  dim3 gw(32, 32);
  wsplit<<<gw, 256, 0, stream>>>(Wq, Wqh, Wql);
  wsplit<<<gw, 256, 0, stream>>>(Wk, Wkh, Wkl);
  wsplit<<<gw, 256, 0, stream>>>(Wv, Wvh, Wvl);

  // ---- projections: M=8192, N=1024, K=1024 --------------------------------
  dim3 g1(ATT_D / BN, (ATT_B * ATT_S) / BM);   // (8, 64)
  gemm_bt<3, 1, 1><<<g1, 256, 0, stream>>>(x, nullptr, Wqh, Wql, Qh, Ql,
      1024, 1024, 1024, 1024, 64, 0, 0, 0);
  gemm_bt<3, 1, 1><<<g1, 256, 0, stream>>>(x, nullptr, Wkh, Wkl, Kh, Kl,
      1024, 1024, 1024, 1024, 64, 0, 0, 0);
  gemm_bt<1, 1, 2><<<g1, 256, 0, stream>>>(x, nullptr, Wvh, nullptr, Vt, nullptr,
      1024, 1024, 1024, 0, 64, 0, 0, 0);

  // ---- attention stripes --------------------------------------------------
  const int np = ATT_S / h;
  for (int p = 0; p < np; ++p) {
    const unsigned short* Ap  = Qh + (size_t)p * h * 1024;
    const unsigned short* Alp = Ql + (size_t)p * h * 1024;
    // scores: per batch M=h, N=2048, K=1024, 3-term, fp32 out
    dim3 gs(ATT_S / BN, ATT_B * h / BM);
    gemm_bt<3, 0, 0><<<gs, 256, 0, stream>>>(Ap, Alp, Kh, Kl, Sbuf, nullptr,
        1024, 1024, 1024, 2048, h / 128,
        (size_t)ATT_S * 1024, (size_t)ATT_S * 1024, (size_t)h * 2048);
    // softmax over B*h rows
    softmax_inplace<<<dim3(ATT_B * h / 4), 256, 0, stream>>>(Sbuf);
    // PV: per batch M=h, N=1024, K=2048, 1-term; A=P bf16 pitch 4096
    dim3 gp(ATT_D / BN, ATT_B * h / BM);
    gemm_bt<1, 0, 0><<<gp, 256, 0, stream>>>((const unsigned short*)Sbuf, nullptr,
        Vt, nullptr, out + (size_t)p * h * 1024, nullptr,
        2048, 4096, 2048, 1024, h / 128,
        (size_t)h * 4096, (size_t)1024 * 2048, (size_t)ATT_S * 1024);
  }
}

// Round 3
// 419.923 us; speedup vs baseline: 21.8787x; 1.0275x over previous
//
#include <hip/hip_runtime.h>
#include <hip/hip_bf16.h>

#define ATT_B 4
#define ATT_S 2048
#define ATT_D 1024

#define BM 128
#define BN 128
#define BK 32

typedef __attribute__((ext_vector_type(8))) short bf16x8;   // MFMA A/B frag (8 bf16)
typedef __attribute__((ext_vector_type(4))) float f32x4;    // MFMA C/D frag
typedef unsigned short ushort_t;

// round-to-nearest-even f32 -> bf16 bits
__device__ inline unsigned short f2bf_rne(float f) {
  unsigned u = __float_as_uint(f);
  u += 0x7FFFu + ((u >> 16) & 1u);
  return (unsigned short)(u >> 16);
}

// async global->LDS, 16B per lane. lds ptr must be wave-uniform.
__device__ inline void gll16(const void* g, void* l) {
  __builtin_amdgcn_global_load_lds(
      (const __attribute__((address_space(1))) void*)g,
      (__attribute__((address_space(3))) void*)l, 16, 0, 0);
}

__device__ __forceinline__ void vwait(int sel) {
  if (sel == 0)      asm volatile("s_waitcnt vmcnt(6)" ::: "memory");
  else if (sel == 1) asm volatile("s_waitcnt vmcnt(4)" ::: "memory");
  else               asm volatile("s_waitcnt vmcnt(0)" ::: "memory");
}

// ===========================================================================
// 256x256 8-wave deep-pipelined GEMM (BK=64 per K-tile, 2 ksteps of 32).
// C[M,N] = A[M,K'] * B[N,K']^T with K' = NTERM*K0 via segment pointer cycle:
//   NTERM=3: A segs {hi,lo,hi}, B segs {hi,hi,lo}  (split-bf16 3-term product)
//   NTERM=1: plain bf16.
// OM=0: fp32 C (batched).  OM=1: hi/lo bf16 out, n<1024 -> (C0,C1), else (C2,C3).
// LDS: A[2dbuf][2khalf][256][32] + B same = 128 KiB, XOR-swizzled
//      (addr ^= ((addr>>7)&3)<<4 within each 16KB k-half block).
// ===========================================================================
template<int NTERM, int OM>
__global__ __launch_bounds__(512, 2)
void gemm256(const ushort_t* __restrict__ Ah, const ushort_t* __restrict__ Al,
             const ushort_t* __restrict__ Bh, const ushort_t* __restrict__ Bl,
             void* __restrict__ C0, void* __restrict__ C1,
             void* __restrict__ C2, void* __restrict__ C3,
             int NT0, int pitchA, int pitchB, int pitchC, int mtiles_pb,
             size_t AbStride, size_t BbStride, size_t CbStride)
{
  extern __shared__ char lds[];   // 131072 bytes at launch
  const int tid  = threadIdx.x;
  const int wave = tid >> 6, lane = tid & 63;
  const int l16  = lane & 15, lh = lane >> 4;
  const int wm   = wave >> 2;          // 0..1  (M half)
  const int wn   = wave & 3;           // 0..3  (N quarter)

  // XCD-aware block swizzle (grids here always have nwg % 8 == 0)
  const int bid = blockIdx.x + gridDim.x * blockIdx.y;
  const int nwg = gridDim.x * gridDim.y;
  const int swz = (bid & 7) * (nwg >> 3) + (bid >> 3);
  const int bx  = swz % gridDim.x;
  const int by  = swz / gridDim.x;

  const int bt   = by / mtiles_pb;
  const int row0 = (by % mtiles_pb) * 256;
  const int col0 = bx * 256;

  const ushort_t* Ahb = Ah + (size_t)bt * AbStride;
  const ushort_t* Alb = (NTERM == 3) ? (Al + (size_t)bt * AbStride) : nullptr;
  const ushort_t* Bhb = Bh + (size_t)bt * BbStride;
  const ushort_t* Blb = (NTERM == 3) ? (Bl + (size_t)bt * BbStride) : nullptr;

  const int NT = NTERM * NT0;

  // segment resolver: tile t -> (A src, B src, k element offset)
  auto srcs = [&](int t, const ushort_t*& As, const ushort_t*& Bs, int& koff) {
    int seg = 0;
    if (NTERM == 3) seg = (t >= 2 * NT0) ? 2 : ((t >= NT0) ? 1 : 0);
    koff = (t - seg * NT0) * 64;
    As = (NTERM == 3 && seg == 1) ? Alb : Ahb;
    Bs = (NTERM == 3 && seg == 2) ? Blb : Bhb;
  };

  // stage one 16KB k-half (256 rows x 32 cols) into LDS; linear dest,
  // inverse-swizzled global source (rule #21).
  auto stage = [&](const ushort_t* src, int rowbase, int pitch, int koff,
                   int kh, int op, int p) {
#pragma unroll
    for (int c = 0; c < 2; ++c) {
      const int chunk = wave + c * 8;
      const int o  = chunk * 1024 + lane * 16;
      const int os = o ^ (((o >> 7) & 3) << 4);
      const int row  = os >> 6;
      const int colb = os & 63;
      const char* g = (const char*)src +
          ((size_t)(rowbase + row) * pitch + koff + kh * 32) * 2 + colb;
      gll16(g, lds + op * 65536 + p * 32768 + kh * 16384 + chunk * 1024);
    }
  };

  auto ldA = [&](int p, int ks, int row) -> bf16x8 {
    int local = row * 64 + lh * 16;
    local ^= ((local >> 7) & 3) << 4;
    return *(const bf16x8*)(lds + p * 32768 + ks * 16384 + local);
  };
  auto ldB = [&](int p, int ks, int row) -> bf16x8 {
    int local = row * 64 + lh * 16;
    local ^= ((local >> 7) & 3) << 4;
    return *(const bf16x8*)(lds + 65536 + p * 32768 + ks * 16384 + local);
  };

  f32x4 acc[8][4] = {};

  // ---- prologue: tile0 (both k-halves) -> buf0; tile1 k-half0 -> buf1 -----
  {
    const ushort_t *As, *Bs; int ko;
    srcs(0, As, Bs, ko);
    stage(As, row0, pitchA, ko, 0, 0, 0);
    stage(Bs, col0, pitchB, ko, 0, 1, 0);
    stage(As, row0, pitchA, ko, 1, 0, 0);
    stage(Bs, col0, pitchB, ko, 1, 1, 0);
    srcs(1, As, Bs, ko);
    stage(As, row0, pitchA, ko, 0, 0, 1);
    stage(Bs, col0, pitchB, ko, 0, 1, 1);
    asm volatile("s_waitcnt vmcnt(8)" ::: "memory");
    __builtin_amdgcn_s_barrier();
  }

  auto mma16 = [&](bf16x8 (&a)[4], bf16x8 (&b)[4], int mh) {
    __builtin_amdgcn_s_setprio(1);
#pragma unroll
    for (int mf = 0; mf < 4; ++mf)
#pragma unroll
      for (int nf = 0; nf < 4; ++nf)
        acc[mh * 4 + mf][nf] = __builtin_amdgcn_mfma_f32_16x16x32_bf16(
            a[mf], b[nf], acc[mh * 4 + mf][nf], 0, 0, 0);
    __builtin_amdgcn_s_setprio(0);
  };

  // ---- main loop: 4 phases per K-tile ------------------------------------
  for (int t = 0; t < NT; ++t) {
    const int p    = t & 1;
    const int vsel = (t < NT - 2) ? 0 : ((t == NT - 2) ? 1 : 2);
    const ushort_t *As1, *Bs1, *As2, *Bs2; int ko1, ko2;
    srcs(t + 1, As1, Bs1, ko1);
    srcs(t + 2, As2, Bs2, ko2);
    const bool st1 = (t + 1 < NT), st2 = (t + 2 < NT);

    bf16x8 a[4], b[4];

    // phase 0: ks=0 mh=0 | stage A-kh1(t+1) -> buf p^1
#pragma unroll
    for (int f = 0; f < 4; ++f) a[f] = ldA(p, 0, wm * 128 + f * 16 + l16);
#pragma unroll
    for (int f = 0; f < 4; ++f) b[f] = ldB(p, 0, wn * 64 + f * 16 + l16);
    if (st1) stage(As1, row0, pitchA, ko1, 1, 0, p ^ 1);
    vwait(vsel); __builtin_amdgcn_s_barrier();
    asm volatile("s_waitcnt lgkmcnt(0)" ::: "memory");
    __builtin_amdgcn_sched_barrier(0);
    mma16(a, b, 0);
    __builtin_amdgcn_s_barrier();

    // phase 1: ks=0 mh=1 (b reused) | stage B-kh1(t+1) -> buf p^1
#pragma unroll
    for (int f = 0; f < 4; ++f) a[f] = ldA(p, 0, wm * 128 + 64 + f * 16 + l16);
    if (st1) stage(Bs1, col0, pitchB, ko1, 1, 1, p ^ 1);
    vwait(vsel); __builtin_amdgcn_s_barrier();
    asm volatile("s_waitcnt lgkmcnt(0)" ::: "memory");
    __builtin_amdgcn_sched_barrier(0);
    mma16(a, b, 1);
    __builtin_amdgcn_s_barrier();

    // phase 2: ks=1 mh=0 | stage A-kh0(t+2) -> buf p
#pragma unroll
    for (int f = 0; f < 4; ++f) a[f] = ldA(p, 1, wm * 128 + f * 16 + l16);
#pragma unroll
    for (int f = 0; f < 4; ++f) b[f] = ldB(p, 1, wn * 64 + f * 16 + l16);
    if (st2) stage(As2, row0, pitchA, ko2, 0, 0, p);
    vwait(vsel); __builtin_amdgcn_s_barrier();
    asm volatile("s_waitcnt lgkmcnt(0)" ::: "memory");
    __builtin_amdgcn_sched_barrier(0);
    mma16(a, b, 0);
    __builtin_amdgcn_s_barrier();

    // phase 3: ks=1 mh=1 (b reused) | stage B-kh0(t+2) -> buf p
#pragma unroll
    for (int f = 0; f < 4; ++f) a[f] = ldA(p, 1, wm * 128 + 64 + f * 16 + l16);
    if (st2) stage(Bs2, col0, pitchB, ko2, 0, 1, p);
    vwait(vsel); __builtin_amdgcn_s_barrier();
    asm volatile("s_waitcnt lgkmcnt(0)" ::: "memory");
    __builtin_amdgcn_sched_barrier(0);
    mma16(a, b, 1);
    __builtin_amdgcn_s_barrier();
  }

  // ---- epilogue (m89-verified frag layout: row=(lh*4+r), col=l16) --------
#pragma unroll
  for (int i = 0; i < 8; ++i) {
    const int mBase = row0 + wm * 128 + (i >> 2) * 64 + (i & 3) * 16 + lh * 4;
#pragma unroll
    for (int nf = 0; nf < 4; ++nf) {
      const int n = col0 + wn * 64 + nf * 16 + l16;
      if (OM == 0) {
        float* Cb = (float*)C0 + (size_t)bt * CbStride;
#pragma unroll
        for (int r = 0; r < 4; ++r)
          Cb[(size_t)(mBase + r) * pitchC + n] = acc[i][nf][r];
      } else {
        ushort_t* Dh = (ushort_t*)((col0 < 1024) ? C0 : C2);
        ushort_t* Dl = (ushort_t*)((col0 < 1024) ? C1 : C3);
        const int nn = (col0 < 1024) ? n : (n - 1024);
#pragma unroll
        for (int r = 0; r < 4; ++r) {
          const float f = acc[i][nf][r];
          const unsigned u = __float_as_uint(f);
          Dh[(size_t)(mBase + r) * pitchC + nn] = (ushort_t)(u >> 16);
          Dl[(size_t)(mBase + r) * pitchC + nn] =
              f2bf_rne(f - __uint_as_float(u & 0xFFFF0000u));
        }
      }
    }
  }
}

// ===========================================================================
// Round-2 proven 128x128 GEMM (kept for V-projection and PV).
// ===========================================================================
template<int NT, int AMODE, int OMODE>
__global__ __launch_bounds__(256, 2)
void gemm_bt(const void* __restrict__ Apv, const void* __restrict__ Alv,
             const ushort_t* __restrict__ Bh, const ushort_t* __restrict__ Bl,
             void* __restrict__ C0, void* __restrict__ C1,
             int K, int pitchA, int pitchB, int pitchC, int mtiles_pb,
             size_t Abstride, size_t Bbstride, size_t Cbstride)
{
  __shared__ ushort_t sAh[BM * BK];
  __shared__ ushort_t sBh[BN * BK];
  __shared__ ushort_t sAl[(NT == 3) ? BM * BK : 8];
  __shared__ ushort_t sBl[(NT == 3) ? BN * BK : 8];

  const int tid  = threadIdx.x;
  const int wave = tid >> 6;
  const int lane = tid & 63;
  const int l16  = lane & 15;
  const int lh   = lane >> 4;
  const int wm   = wave >> 1;
  const int wn   = wave & 1;

  const int bt   = blockIdx.y / mtiles_pb;
  const int ml   = blockIdx.y % mtiles_pb;
  const int row0 = ml * BM;
  const int col0 = blockIdx.x * BN;

  const ushort_t* Bhb = Bh + (size_t)bt * Bbstride;
  const ushort_t* Blb = (NT == 3) ? (Bl + (size_t)bt * Bbstride) : nullptr;

  const ushort_t* Ahb = nullptr;
  const ushort_t* Alb = nullptr;
  const float*    Af  = nullptr;
  if (AMODE == 0) {
    Ahb = (const ushort_t*)Apv + (size_t)bt * Abstride;
    if (NT == 3) Alb = (const ushort_t*)Alv + (size_t)bt * Abstride;
  } else {
    Af = (const float*)Apv + (size_t)bt * Abstride;
  }

  f32x4 acc[4][4] = {};

  for (int k0 = 0; k0 < K; k0 += BK) {
#pragma unroll
    for (int j = 0; j < 2; ++j) {
      const int off = tid * 16 + j * 4096;
      const int r   = off >> 6;
      const int kb  = off & 63;
      const char* g = (const char*)Bhb + ((size_t)(col0 + r) * pitchB + k0) * 2 + kb;
      gll16(g, (char*)sBh + (wave << 10) + j * 4096);
    }
    if (AMODE == 0) {
#pragma unroll
      for (int j = 0; j < 2; ++j) {
        const int off = tid * 16 + j * 4096;
        const int r   = off >> 6;
        const int kb  = off & 63;
        const char* g = (const char*)Ahb + ((size_t)(row0 + r) * pitchA + k0) * 2 + kb;
        gll16(g, (char*)sAh + (wave << 10) + j * 4096);
      }
    } else {
#pragma unroll
      for (int j = 0; j < 4; ++j) {
        const int lin4 = tid + j * 256;
        const int r    = lin4 >> 3;
        const int c4   = lin4 & 7;
        const float4 v = *(const float4*)(Af + (size_t)(row0 + r) * pitchA + k0 + c4 * 4);
        const unsigned ux = __float_as_uint(v.x), uy = __float_as_uint(v.y);
        const unsigned uz = __float_as_uint(v.z), uw = __float_as_uint(v.w);
        ushort4 hi;
        hi.x = (ushort_t)(ux >> 16); hi.y = (ushort_t)(uy >> 16);
        hi.z = (ushort_t)(uz >> 16); hi.w = (ushort_t)(uw >> 16);
        *(ushort4*)&sAh[r * BK + c4 * 4] = hi;
      }
    }
    __syncthreads();

    bf16x8 ah[4], bh4[4];
#pragma unroll
    for (int t = 0; t < 4; ++t) {
      ah[t]  = *(const bf16x8*)&sAh[(wm * 64 + t * 16 + l16) * BK + lh * 8];
      bh4[t] = *(const bf16x8*)&sBh[(wn * 64 + t * 16 + l16) * BK + lh * 8];
    }
#pragma unroll
    for (int i = 0; i < 4; ++i)
#pragma unroll
      for (int j = 0; j < 4; ++j)
        acc[i][j] = __builtin_amdgcn_mfma_f32_16x16x32_bf16(ah[i], bh4[j], acc[i][j], 0, 0, 0);
    __syncthreads();
  }

#pragma unroll
  for (int i = 0; i < 4; ++i) {
    const int mBase = row0 + wm * 64 + i * 16 + lh * 4;
#pragma unroll
    for (int j = 0; j < 4; ++j) {
      const int n = col0 + wn * 64 + j * 16 + l16;
      if (OMODE == 0) {
        float* C = (float*)C0 + (size_t)bt * Cbstride;
#pragma unroll
        for (int r = 0; r < 4; ++r)
          C[(size_t)(mBase + r) * pitchC + n] = acc[i][j][r];
      } else {
        // V^T store: Vt[batch][n][srow]
        ushort_t* Vt = (ushort_t*)C0;
        const int b2 = mBase >> 11;
        const int sr = mBase & 2047;
        ushort4 o;
        o.x = f2bf_rne(acc[i][j][0]); o.y = f2bf_rne(acc[i][j][1]);
        o.z = f2bf_rne(acc[i][j][2]); o.w = f2bf_rne(acc[i][j][3]);
        *(ushort4*)&Vt[(size_t)b2 * (1024u * 2048u) + (size_t)n * 2048 + sr] = o;
      }
    }
  }
}

// ---------------------------------------------------------------------------
// W [1024][1024] fp32 -> Wh/Wl bf16 [n][k] (transposed, split)
// ---------------------------------------------------------------------------
__global__ __launch_bounds__(256)
void wsplit(const float* __restrict__ W, ushort_t* __restrict__ Wh,
            ushort_t* __restrict__ Wl) {
  __shared__ float t[32][33];
  const int k0 = blockIdx.x * 32;
  const int n0 = blockIdx.y * 32;
  const int tx = threadIdx.x & 31;
  const int ty = threadIdx.x >> 5;
#pragma unroll
  for (int i = 0; i < 32; i += 8)
    t[ty + i][tx] = W[(size_t)(k0 + ty + i) * 1024 + (n0 + tx)];
  __syncthreads();
#pragma unroll
  for (int i = 0; i < 32; i += 8) {
    const float f = t[tx][ty + i];
    const unsigned u = __float_as_uint(f);
    Wh[(size_t)(n0 + ty + i) * 1024 + (k0 + tx)] = (ushort_t)(u >> 16);
    Wl[(size_t)(n0 + ty + i) * 1024 + (k0 + tx)] =
        f2bf_rne(f - __uint_as_float(u & 0xFFFF0000u));
  }
}

// ---------------------------------------------------------------------------
// x fp32 [8192*1024] -> Xh, Xl bf16
// ---------------------------------------------------------------------------
__global__ __launch_bounds__(256)
void xsplit(const float* __restrict__ x, ushort_t* __restrict__ Xh,
            ushort_t* __restrict__ Xl) {
  const size_t i0 = ((size_t)blockIdx.x * 256 + threadIdx.x) * 16;
#pragma unroll
  for (int j = 0; j < 4; ++j) {
    const float4 v = *(const float4*)(x + i0 + j * 4);
    const unsigned ux = __float_as_uint(v.x), uy = __float_as_uint(v.y);
    const unsigned uz = __float_as_uint(v.z), uw = __float_as_uint(v.w);
    ushort4 hi, lo;
    hi.x = (ushort_t)(ux >> 16); hi.y = (ushort_t)(uy >> 16);
    hi.z = (ushort_t)(uz >> 16); hi.w = (ushort_t)(uw >> 16);
    lo.x = f2bf_rne(v.x - __uint_as_float(ux & 0xFFFF0000u));
    lo.y = f2bf_rne(v.y - __uint_as_float(uy & 0xFFFF0000u));
    lo.z = f2bf_rne(v.z - __uint_as_float(uz & 0xFFFF0000u));
    lo.w = f2bf_rne(v.w - __uint_as_float(uw & 0xFFFF0000u));
    *(ushort4*)(Xh + i0 + j * 4) = hi;
    *(ushort4*)(Xl + i0 + j * 4) = lo;
  }
}

// ---------------------------------------------------------------------------
// Row softmax in place: 2048 fp32 scores -> 2048 bf16 P (start of same row).
// ---------------------------------------------------------------------------
__global__ __launch_bounds__(256)
void softmax_inplace(float* __restrict__ S) {
  const int wave = threadIdx.x >> 6;
  const int lane = threadIdx.x & 63;
  float* rp = S + ((size_t)blockIdx.x * 4 + wave) * 2048;

  float4 v[8];
#pragma unroll
  for (int i = 0; i < 8; ++i) v[i] = *(const float4*)&rp[lane * 4 + i * 256];

  float m = -1e30f;
#pragma unroll
  for (int i = 0; i < 8; ++i)
    m = fmaxf(m, fmaxf(fmaxf(v[i].x, v[i].y), fmaxf(v[i].z, v[i].w)));
#pragma unroll
  for (int s = 32; s; s >>= 1) m = fmaxf(m, __shfl_xor(m, s));

  float sum = 0.f;
#pragma unroll
  for (int i = 0; i < 8; ++i) {
    v[i].x = __expf(v[i].x - m); v[i].y = __expf(v[i].y - m);
    v[i].z = __expf(v[i].z - m); v[i].w = __expf(v[i].w - m);
    sum += (v[i].x + v[i].y) + (v[i].z + v[i].w);
  }
#pragma unroll
  for (int s = 32; s; s >>= 1) sum += __shfl_xor(sum, s);
  const float inv = 1.0f / sum;

  ushort_t* pp = (ushort_t*)rp;
#pragma unroll
  for (int i = 0; i < 8; ++i) {
    ushort4 o;
    o.x = f2bf_rne(v[i].x * inv); o.y = f2bf_rne(v[i].y * inv);
    o.z = f2bf_rne(v[i].z * inv); o.w = f2bf_rne(v[i].w * inv);
    *(ushort4*)&pp[lane * 4 + i * 256] = o;
  }
}

// ---------------------------------------------------------------------------
extern "C" void kernel_launch(void* const* d_in, const int* in_sizes, int n_in,
                              void* d_out, int out_size, void* d_ws, size_t ws_size,
                              hipStream_t stream) {
  const float* x  = (const float*)d_in[0];
  const float* Wq = (const float*)d_in[1];
  const float* Wk = (const float*)d_in[2];
  const float* Wv = (const float*)d_in[3];
  float* out = (float*)d_out;

  char* ws = (char*)d_ws;
  const size_t MB = 1024 * 1024;
  ushort_t* Qh = (ushort_t*)(ws +  0 * MB);
  ushort_t* Ql = (ushort_t*)(ws + 16 * MB);
  ushort_t* Kh = (ushort_t*)(ws + 32 * MB);
  ushort_t* Kl = (ushort_t*)(ws + 48 * MB);
  ushort_t* Vt = (ushort_t*)(ws + 64 * MB);
  // transient region (dead once scores are computed):
  ushort_t* Xh   = (ushort_t*)(ws +  80 * MB);
  ushort_t* Xl   = (ushort_t*)(ws +  96 * MB);
  ushort_t* Wqkh = (ushort_t*)(ws + 112 * MB);   // 2048x1024 (Wq^T ; Wk^T) hi
  ushort_t* Wqkl = (ushort_t*)(ws + 116 * MB);
  ushort_t* Wvh  = (ushort_t*)(ws + 120 * MB);
  ushort_t* Wvl  = (ushort_t*)(ws + 122 * MB);
  float* Sbuf = (float*)(ws + 80 * MB);

  // stripe height for the scores buffer
  const size_t avail = (ws_size > 80 * MB) ? (ws_size - 80 * MB) : 0;
  int h = 256;
  const int cands[4] = {2048, 1024, 512, 256};
  for (int c = 0; c < 4; ++c)
    if ((size_t)4 * cands[c] * 2048 * 4 <= avail) { h = cands[c]; break; }

  // ---- preprocessing ------------------------------------------------------
  dim3 gw(32, 32);
  wsplit<<<gw, 256, 0, stream>>>(Wq, Wqkh, Wqkl);
  wsplit<<<gw, 256, 0, stream>>>(Wk, Wqkh + 1024 * 1024, Wqkl + 1024 * 1024);
  wsplit<<<gw, 256, 0, stream>>>(Wv, Wvh, Wvl);
  xsplit<<<2048, 256, 0, stream>>>(x, Xh, Xl);

  // ---- fused Q+K projection: M=8192, N=2048, K'=3*1024 (8-phase 256²) -----
  gemm256<3, 1><<<dim3(8, 32), 512, 131072, stream>>>(
      Xh, Xl, Wqkh, Wqkl, Qh, Ql, Kh, Kl,
      16, 1024, 1024, 1024, 32, 0, 0, 0);

  // ---- V projection (proven 128² path, transposed store) ------------------
  gemm_bt<1, 1, 2><<<dim3(8, 64), 256, 0, stream>>>(
      x, nullptr, Wvh, nullptr, Vt, nullptr,
      1024, 1024, 1024, 0, 64, 0, 0, 0);

  // ---- attention stripes --------------------------------------------------
  const int np = ATT_S / h;
  for (int p = 0; p < np; ++p) {
    // scores: per batch M=h, N=2048, K'=3*1024, fp32 out (8-phase 256²)
    gemm256<3, 0><<<dim3(8, ATT_B * h / 256), 512, 131072, stream>>>(
        Qh + (size_t)p * h * 1024, Ql + (size_t)p * h * 1024, Kh, Kl,
        Sbuf, nullptr, nullptr, nullptr,
        16, 1024, 1024, 2048, h / 256,
        (size_t)ATT_S * 1024, (size_t)ATT_S * 1024, (size_t)h * 2048);
    // softmax over B*h rows
    softmax_inplace<<<dim3(ATT_B * h / 4), 256, 0, stream>>>(Sbuf);
    // PV: per batch M=h, N=1024, K=2048 (proven 128² path); A=P bf16 pitch 4096
    gemm_bt<1, 0, 0><<<dim3(8, ATT_B * h / 128), 256, 0, stream>>>(
        (const ushort_t*)Sbuf, nullptr, Vt, nullptr,
        out + (size_t)p * h * 1024, nullptr,
        2048, 4096, 2048, 1024, h / 128,
        (size_t)h * 4096, (size_t)1024 * 2048, (size_t)ATT_S * 1024);
  }
}

// Round 4
// 413.998 us; speedup vs baseline: 22.1918x; 1.0143x over previous
//
#include <hip/hip_runtime.h>
#include <hip/hip_bf16.h>

#define ATT_B 4
#define ATT_S 2048
#define ATT_D 1024

#define BM 128
#define BN 128
#define BK 32

typedef __attribute__((ext_vector_type(8))) short bf16x8;   // MFMA A/B frag (8 bf16)
typedef __attribute__((ext_vector_type(4))) float f32x4;    // MFMA C/D frag
typedef unsigned short ushort_t;

// round-to-nearest-even f32 -> bf16 bits
__device__ inline unsigned short f2bf_rne(float f) {
  unsigned u = __float_as_uint(f);
  u += 0x7FFFu + ((u >> 16) & 1u);
  return (unsigned short)(u >> 16);
}

// async global->LDS, 16B per lane. lds ptr must be wave-uniform.
__device__ inline void gll16(const void* g, void* l) {
  __builtin_amdgcn_global_load_lds(
      (const __attribute__((address_space(1))) void*)g,
      (__attribute__((address_space(3))) void*)l, 16, 0, 0);
}

// ===========================================================================
// 256x256 8-wave deep-pipelined GEMM (BK=64 per K-tile, 2 ksteps of 32).
// C[M,N] = A[M,K'] * B[N,K']^T with K' = NTERM*K0 via segment pointer cycle:
//   NTERM=3: A segs {hi,lo,hi}, B segs {hi,hi,lo}  (split-bf16 3-term product)
// OM=0: fp32 C (batched).  OM=1: hi/lo bf16 out, n<1024 -> (C0,C1), else (C2,C3).
// Counted-vmcnt schedule (T4): ONE vmcnt per K-tile at phase 3:
//   t < NT-2 -> vmcnt(4); t == NT-2 -> vmcnt(0); t == NT-1 -> none.
// (vmcnt(4) at iter t guarantees all 4 half-tiles consumed by iter t+1:
//  youngest needed = B-kh1(t+1), exactly 2 stage-calls = 4 loads after it.)
// ===========================================================================
template<int NTERM, int OM>
__global__ __launch_bounds__(512, 2)
void gemm256(const ushort_t* __restrict__ Ah, const ushort_t* __restrict__ Al,
             const ushort_t* __restrict__ Bh, const ushort_t* __restrict__ Bl,
             void* __restrict__ C0, void* __restrict__ C1,
             void* __restrict__ C2, void* __restrict__ C3,
             int NT0, int pitchA, int pitchB, int pitchC, int mtiles_pb,
             size_t AbStride, size_t BbStride, size_t CbStride)
{
  extern __shared__ char lds[];   // 131072 bytes at launch
  const int tid  = threadIdx.x;
  const int wave = tid >> 6, lane = tid & 63;
  const int l16  = lane & 15, lh = lane >> 4;
  const int wm   = wave >> 2;          // 0..1  (M half)
  const int wn   = wave & 3;           // 0..3  (N quarter)

  // XCD-aware block swizzle (grids here always have nwg % 8 == 0)
  const int bid = blockIdx.x + gridDim.x * blockIdx.y;
  const int nwg = gridDim.x * gridDim.y;
  const int swz = (bid & 7) * (nwg >> 3) + (bid >> 3);
  const int bx  = swz % gridDim.x;
  const int by  = swz / gridDim.x;

  const int bt   = by / mtiles_pb;
  const int row0 = (by % mtiles_pb) * 256;
  const int col0 = bx * 256;

  const ushort_t* Ahb = Ah + (size_t)bt * AbStride;
  const ushort_t* Alb = (NTERM == 3) ? (Al + (size_t)bt * AbStride) : nullptr;
  const ushort_t* Bhb = Bh + (size_t)bt * BbStride;
  const ushort_t* Blb = (NTERM == 3) ? (Bl + (size_t)bt * BbStride) : nullptr;

  const int NT = NTERM * NT0;

  // segment resolver: tile t -> (A src, B src, k element offset)
  auto srcs = [&](int t, const ushort_t*& As, const ushort_t*& Bs, int& koff) {
    int seg = 0;
    if (NTERM == 3) seg = (t >= 2 * NT0) ? 2 : ((t >= NT0) ? 1 : 0);
    koff = (t - seg * NT0) * 64;
    As = (NTERM == 3 && seg == 1) ? Alb : Ahb;
    Bs = (NTERM == 3 && seg == 2) ? Blb : Bhb;
  };

  // stage one 16KB k-half (256 rows x 32 cols) into LDS; linear dest,
  // inverse-swizzled global source (rule #21).
  auto stage = [&](const ushort_t* src, int rowbase, int pitch, int koff,
                   int kh, int op, int p) {
#pragma unroll
    for (int c = 0; c < 2; ++c) {
      const int chunk = wave + c * 8;
      const int o  = chunk * 1024 + lane * 16;
      const int os = o ^ (((o >> 7) & 3) << 4);
      const int row  = os >> 6;
      const int colb = os & 63;
      const char* g = (const char*)src +
          ((size_t)(rowbase + row) * pitch + koff + kh * 32) * 2 + colb;
      gll16(g, lds + op * 65536 + p * 32768 + kh * 16384 + chunk * 1024);
    }
  };

  auto ldA = [&](int p, int ks, int row) -> bf16x8 {
    int local = row * 64 + lh * 16;
    local ^= ((local >> 7) & 3) << 4;
    return *(const bf16x8*)(lds + p * 32768 + ks * 16384 + local);
  };
  auto ldB = [&](int p, int ks, int row) -> bf16x8 {
    int local = row * 64 + lh * 16;
    local ^= ((local >> 7) & 3) << 4;
    return *(const bf16x8*)(lds + 65536 + p * 32768 + ks * 16384 + local);
  };

  f32x4 acc[8][4] = {};

  // ---- prologue: tile0 (both k-halves) -> buf0; tile1 k-half0 -> buf1 -----
  {
    const ushort_t *As, *Bs; int ko;
    srcs(0, As, Bs, ko);
    stage(As, row0, pitchA, ko, 0, 0, 0);
    stage(Bs, col0, pitchB, ko, 0, 1, 0);
    stage(As, row0, pitchA, ko, 1, 0, 0);
    stage(Bs, col0, pitchB, ko, 1, 1, 0);
    srcs(1, As, Bs, ko);
    stage(As, row0, pitchA, ko, 0, 0, 1);
    stage(Bs, col0, pitchB, ko, 0, 1, 1);
    asm volatile("s_waitcnt vmcnt(4)" ::: "memory");   // land ALL of tile 0
    __builtin_amdgcn_s_barrier();
  }

  auto mma16 = [&](bf16x8 (&a)[4], bf16x8 (&b)[4], int mh) {
    __builtin_amdgcn_s_setprio(1);
#pragma unroll
    for (int mf = 0; mf < 4; ++mf)
#pragma unroll
      for (int nf = 0; nf < 4; ++nf)
        acc[mh * 4 + mf][nf] = __builtin_amdgcn_mfma_f32_16x16x32_bf16(
            a[mf], b[nf], acc[mh * 4 + mf][nf], 0, 0, 0);
    __builtin_amdgcn_s_setprio(0);
  };

  // ---- main loop: 4 phases per K-tile, ONE counted vmcnt at phase 3 ------
  for (int t = 0; t < NT; ++t) {
    const int p = t & 1;
    const ushort_t *As1, *Bs1, *As2, *Bs2; int ko1, ko2;
    srcs(t + 1, As1, Bs1, ko1);
    srcs(t + 2, As2, Bs2, ko2);
    const bool st1 = (t + 1 < NT), st2 = (t + 2 < NT);

    bf16x8 a[4], b[4];

    // phase 0: ks=0 mh=0 | stage A-kh1(t+1) -> buf p^1
#pragma unroll
    for (int f = 0; f < 4; ++f) a[f] = ldA(p, 0, wm * 128 + f * 16 + l16);
#pragma unroll
    for (int f = 0; f < 4; ++f) b[f] = ldB(p, 0, wn * 64 + f * 16 + l16);
    if (st1) stage(As1, row0, pitchA, ko1, 1, 0, p ^ 1);
    __builtin_amdgcn_s_barrier();
    asm volatile("s_waitcnt lgkmcnt(0)" ::: "memory");
    __builtin_amdgcn_sched_barrier(0);
    mma16(a, b, 0);
    __builtin_amdgcn_s_barrier();

    // phase 1: ks=0 mh=1 (b reused) | stage B-kh1(t+1) -> buf p^1
#pragma unroll
    for (int f = 0; f < 4; ++f) a[f] = ldA(p, 0, wm * 128 + 64 + f * 16 + l16);
    if (st1) stage(Bs1, col0, pitchB, ko1, 1, 1, p ^ 1);
    __builtin_amdgcn_s_barrier();
    asm volatile("s_waitcnt lgkmcnt(0)" ::: "memory");
    __builtin_amdgcn_sched_barrier(0);
    mma16(a, b, 1);
    __builtin_amdgcn_s_barrier();

    // phase 2: ks=1 mh=0 | stage A-kh0(t+2) -> buf p
#pragma unroll
    for (int f = 0; f < 4; ++f) a[f] = ldA(p, 1, wm * 128 + f * 16 + l16);
#pragma unroll
    for (int f = 0; f < 4; ++f) b[f] = ldB(p, 1, wn * 64 + f * 16 + l16);
    if (st2) stage(As2, row0, pitchA, ko2, 0, 0, p);
    __builtin_amdgcn_s_barrier();
    asm volatile("s_waitcnt lgkmcnt(0)" ::: "memory");
    __builtin_amdgcn_sched_barrier(0);
    mma16(a, b, 0);
    __builtin_amdgcn_s_barrier();

    // phase 3: ks=1 mh=1 (b reused) | stage B-kh0(t+2) -> buf p | vmcnt
#pragma unroll
    for (int f = 0; f < 4; ++f) a[f] = ldA(p, 1, wm * 128 + 64 + f * 16 + l16);
    if (st2) stage(Bs2, col0, pitchB, ko2, 0, 1, p);
    if (t < NT - 2)       asm volatile("s_waitcnt vmcnt(4)" ::: "memory");
    else if (t == NT - 2) asm volatile("s_waitcnt vmcnt(0)" ::: "memory");
    __builtin_amdgcn_s_barrier();
    asm volatile("s_waitcnt lgkmcnt(0)" ::: "memory");
    __builtin_amdgcn_sched_barrier(0);
    mma16(a, b, 1);
    __builtin_amdgcn_s_barrier();
  }

  // ---- epilogue (m89-verified frag layout: row=(lh*4+r), col=l16) --------
#pragma unroll
  for (int i = 0; i < 8; ++i) {
    const int mBase = row0 + wm * 128 + (i >> 2) * 64 + (i & 3) * 16 + lh * 4;
#pragma unroll
    for (int nf = 0; nf < 4; ++nf) {
      const int n = col0 + wn * 64 + nf * 16 + l16;
      if (OM == 0) {
        float* Cb = (float*)C0 + (size_t)bt * CbStride;
#pragma unroll
        for (int r = 0; r < 4; ++r)
          Cb[(size_t)(mBase + r) * pitchC + n] = acc[i][nf][r];
      } else {
        ushort_t* Dh = (ushort_t*)((col0 < 1024) ? C0 : C2);
        ushort_t* Dl = (ushort_t*)((col0 < 1024) ? C1 : C3);
        const int nn = (col0 < 1024) ? n : (n - 1024);
#pragma unroll
        for (int r = 0; r < 4; ++r) {
          const float f = acc[i][nf][r];
          const unsigned u = __float_as_uint(f);
          Dh[(size_t)(mBase + r) * pitchC + nn] = (ushort_t)(u >> 16);
          Dl[(size_t)(mBase + r) * pitchC + nn] =
              f2bf_rne(f - __uint_as_float(u & 0xFFFF0000u));
        }
      }
    }
  }
}

// ===========================================================================
// Proven 128x128 GEMM (V-projection, PV).
// ===========================================================================
template<int NT, int AMODE, int OMODE>
__global__ __launch_bounds__(256, 2)
void gemm_bt(const void* __restrict__ Apv, const void* __restrict__ Alv,
             const ushort_t* __restrict__ Bh, const ushort_t* __restrict__ Bl,
             void* __restrict__ C0, void* __restrict__ C1,
             int K, int pitchA, int pitchB, int pitchC, int mtiles_pb,
             size_t Abstride, size_t Bbstride, size_t Cbstride)
{
  __shared__ ushort_t sAh[BM * BK];
  __shared__ ushort_t sBh[BN * BK];

  const int tid  = threadIdx.x;
  const int wave = tid >> 6;
  const int lane = tid & 63;
  const int l16  = lane & 15;
  const int lh   = lane >> 4;
  const int wm   = wave >> 1;
  const int wn   = wave & 1;

  const int bt   = blockIdx.y / mtiles_pb;
  const int ml   = blockIdx.y % mtiles_pb;
  const int row0 = ml * BM;
  const int col0 = blockIdx.x * BN;

  const ushort_t* Bhb = Bh + (size_t)bt * Bbstride;

  const ushort_t* Ahb = nullptr;
  const float*    Af  = nullptr;
  if (AMODE == 0) Ahb = (const ushort_t*)Apv + (size_t)bt * Abstride;
  else            Af  = (const float*)Apv + (size_t)bt * Abstride;

  f32x4 acc[4][4] = {};

  for (int k0 = 0; k0 < K; k0 += BK) {
#pragma unroll
    for (int j = 0; j < 2; ++j) {
      const int off = tid * 16 + j * 4096;
      const int r   = off >> 6;
      const int kb  = off & 63;
      const char* g = (const char*)Bhb + ((size_t)(col0 + r) * pitchB + k0) * 2 + kb;
      gll16(g, (char*)sBh + (wave << 10) + j * 4096);
    }
    if (AMODE == 0) {
#pragma unroll
      for (int j = 0; j < 2; ++j) {
        const int off = tid * 16 + j * 4096;
        const int r   = off >> 6;
        const int kb  = off & 63;
        const char* g = (const char*)Ahb + ((size_t)(row0 + r) * pitchA + k0) * 2 + kb;
        gll16(g, (char*)sAh + (wave << 10) + j * 4096);
      }
    } else {
#pragma unroll
      for (int j = 0; j < 4; ++j) {
        const int lin4 = tid + j * 256;
        const int r    = lin4 >> 3;
        const int c4   = lin4 & 7;
        const float4 v = *(const float4*)(Af + (size_t)(row0 + r) * pitchA + k0 + c4 * 4);
        ushort4 hi;
        hi.x = (ushort_t)(__float_as_uint(v.x) >> 16);
        hi.y = (ushort_t)(__float_as_uint(v.y) >> 16);
        hi.z = (ushort_t)(__float_as_uint(v.z) >> 16);
        hi.w = (ushort_t)(__float_as_uint(v.w) >> 16);
        *(ushort4*)&sAh[r * BK + c4 * 4] = hi;
      }
    }
    __syncthreads();

    bf16x8 ah[4], bh4[4];
#pragma unroll
    for (int t = 0; t < 4; ++t) {
      ah[t]  = *(const bf16x8*)&sAh[(wm * 64 + t * 16 + l16) * BK + lh * 8];
      bh4[t] = *(const bf16x8*)&sBh[(wn * 64 + t * 16 + l16) * BK + lh * 8];
    }
#pragma unroll
    for (int i = 0; i < 4; ++i)
#pragma unroll
      for (int j = 0; j < 4; ++j)
        acc[i][j] = __builtin_amdgcn_mfma_f32_16x16x32_bf16(ah[i], bh4[j], acc[i][j], 0, 0, 0);
    __syncthreads();
  }

#pragma unroll
  for (int i = 0; i < 4; ++i) {
    const int mBase = row0 + wm * 64 + i * 16 + lh * 4;
#pragma unroll
    for (int j = 0; j < 4; ++j) {
      const int n = col0 + wn * 64 + j * 16 + l16;
      if (OMODE == 0) {
        float* C = (float*)C0 + (size_t)bt * Cbstride;
#pragma unroll
        for (int r = 0; r < 4; ++r)
          C[(size_t)(mBase + r) * pitchC + n] = acc[i][j][r];
      } else {
        // V^T store: Vt[batch][n][srow]
        ushort_t* Vt = (ushort_t*)C0;
        const int b2 = mBase >> 11;
        const int sr = mBase & 2047;
        ushort4 o;
        o.x = f2bf_rne(acc[i][j][0]); o.y = f2bf_rne(acc[i][j][1]);
        o.z = f2bf_rne(acc[i][j][2]); o.w = f2bf_rne(acc[i][j][3]);
        *(ushort4*)&Vt[(size_t)b2 * (1024u * 2048u) + (size_t)n * 2048 + sr] = o;
      }
    }
  }
}

// ---------------------------------------------------------------------------
// W [1024][1024] fp32 -> Wh/Wl bf16 [n][k] (transposed, split)
// ---------------------------------------------------------------------------
__global__ __launch_bounds__(256)
void wsplit(const float* __restrict__ W, ushort_t* __restrict__ Wh,
            ushort_t* __restrict__ Wl) {
  __shared__ float t[32][33];
  const int k0 = blockIdx.x * 32;
  const int n0 = blockIdx.y * 32;
  const int tx = threadIdx.x & 31;
  const int ty = threadIdx.x >> 5;
#pragma unroll
  for (int i = 0; i < 32; i += 8)
    t[ty + i][tx] = W[(size_t)(k0 + ty + i) * 1024 + (n0 + tx)];
  __syncthreads();
#pragma unroll
  for (int i = 0; i < 32; i += 8) {
    const float f = t[tx][ty + i];
    const unsigned u = __float_as_uint(f);
    Wh[(size_t)(n0 + ty + i) * 1024 + (k0 + tx)] = (ushort_t)(u >> 16);
    Wl[(size_t)(n0 + ty + i) * 1024 + (k0 + tx)] =
        f2bf_rne(f - __uint_as_float(u & 0xFFFF0000u));
  }
}

// ---------------------------------------------------------------------------
// x fp32 [8192*1024] -> Xh, Xl bf16
// ---------------------------------------------------------------------------
__global__ __launch_bounds__(256)
void xsplit(const float* __restrict__ x, ushort_t* __restrict__ Xh,
            ushort_t* __restrict__ Xl) {
  const size_t i0 = ((size_t)blockIdx.x * 256 + threadIdx.x) * 16;
#pragma unroll
  for (int j = 0; j < 4; ++j) {
    const float4 v = *(const float4*)(x + i0 + j * 4);
    const unsigned ux = __float_as_uint(v.x), uy = __float_as_uint(v.y);
    const unsigned uz = __float_as_uint(v.z), uw = __float_as_uint(v.w);
    ushort4 hi, lo;
    hi.x = (ushort_t)(ux >> 16); hi.y = (ushort_t)(uy >> 16);
    hi.z = (ushort_t)(uz >> 16); hi.w = (ushort_t)(uw >> 16);
    lo.x = f2bf_rne(v.x - __uint_as_float(ux & 0xFFFF0000u));
    lo.y = f2bf_rne(v.y - __uint_as_float(uy & 0xFFFF0000u));
    lo.z = f2bf_rne(v.z - __uint_as_float(uz & 0xFFFF0000u));
    lo.w = f2bf_rne(v.w - __uint_as_float(uw & 0xFFFF0000u));
    *(ushort4*)(Xh + i0 + j * 4) = hi;
    *(ushort4*)(Xl + i0 + j * 4) = lo;
  }
}

// ---------------------------------------------------------------------------
// Row softmax in place: 2048 fp32 scores -> 2048 bf16 P (start of same row).
// ---------------------------------------------------------------------------
__global__ __launch_bounds__(256)
void softmax_inplace(float* __restrict__ S) {
  const int wave = threadIdx.x >> 6;
  const int lane = threadIdx.x & 63;
  float* rp = S + ((size_t)blockIdx.x * 4 + wave) * 2048;

  float4 v[8];
#pragma unroll
  for (int i = 0; i < 8; ++i) v[i] = *(const float4*)&rp[lane * 4 + i * 256];

  float m = -1e30f;
#pragma unroll
  for (int i = 0; i < 8; ++i)
    m = fmaxf(m, fmaxf(fmaxf(v[i].x, v[i].y), fmaxf(v[i].z, v[i].w)));
#pragma unroll
  for (int s = 32; s; s >>= 1) m = fmaxf(m, __shfl_xor(m, s));

  float sum = 0.f;
#pragma unroll
  for (int i = 0; i < 8; ++i) {
    v[i].x = __expf(v[i].x - m); v[i].y = __expf(v[i].y - m);
    v[i].z = __expf(v[i].z - m); v[i].w = __expf(v[i].w - m);
    sum += (v[i].x + v[i].y) + (v[i].z + v[i].w);
  }
#pragma unroll
  for (int s = 32; s; s >>= 1) sum += __shfl_xor(sum, s);
  const float inv = 1.0f / sum;

  ushort_t* pp = (ushort_t*)rp;
#pragma unroll
  for (int i = 0; i < 8; ++i) {
    ushort4 o;
    o.x = f2bf_rne(v[i].x * inv); o.y = f2bf_rne(v[i].y * inv);
    o.z = f2bf_rne(v[i].z * inv); o.w = f2bf_rne(v[i].w * inv);
    *(ushort4*)&pp[lane * 4 + i * 256] = o;
  }
}

// ---------------------------------------------------------------------------
extern "C" void kernel_launch(void* const* d_in, const int* in_sizes, int n_in,
                              void* d_out, int out_size, void* d_ws, size_t ws_size,
                              hipStream_t stream) {
  const float* x  = (const float*)d_in[0];
  const float* Wq = (const float*)d_in[1];
  const float* Wk = (const float*)d_in[2];
  const float* Wv = (const float*)d_in[3];
  float* out = (float*)d_out;

  char* ws = (char*)d_ws;
  char* ob = (char*)d_out;
  const size_t MB = 1024 * 1024;

  // persistent QK (hi/lo): [0,64) MB
  ushort_t* Qh = (ushort_t*)(ws +  0 * MB);
  ushort_t* Ql = (ushort_t*)(ws + 16 * MB);
  ushort_t* Kh = (ushort_t*)(ws + 32 * MB);
  ushort_t* Kl = (ushort_t*)(ws + 48 * MB);
  // transient X (dead once scores run): [64,96) MB
  ushort_t* Xh = (ushort_t*)(ws + 64 * MB);
  ushort_t* Xl = (ushort_t*)(ws + 80 * MB);
  // W slabs live in d_out (dead before PV, which fully rewrites d_out)
  ushort_t* Wqkh = (ushort_t*)(ob + 0 * MB);   // 4MB: Wq^T hi | Wk^T hi
  ushort_t* Wqkl = (ushort_t*)(ob + 4 * MB);   // 4MB
  ushort_t* Wvh  = (ushort_t*)(ob + 8 * MB);   // 2MB
  ushort_t* Wvl  = (ushort_t*)(ob + 10 * MB);  // 2MB (unused after split)

  // ---- shared preprocessing ----------------------------------------------
  dim3 gw(32, 32);
  wsplit<<<gw, 256, 0, stream>>>(Wq, Wqkh, Wqkl);
  wsplit<<<gw, 256, 0, stream>>>(Wk, Wqkh + 1024 * 1024, Wqkl + 1024 * 1024);
  wsplit<<<gw, 256, 0, stream>>>(Wv, Wvh, Wvl);
  xsplit<<<2048, 256, 0, stream>>>(x, Xh, Xl);

  // ---- fused Q+K projection: M=8192, N=2048, K'=3*1024 --------------------
  gemm256<3, 1><<<dim3(8, 32), 512, 131072, stream>>>(
      Xh, Xl, Wqkh, Wqkl, Qh, Ql, Kh, Kl,
      16, 1024, 1024, 1024, 32, 0, 0, 0);

  if (ws_size >= 128 * MB) {
    // ===== Tier B': single-dispatch full-S scores (256 wg) =================
    float* Sbuf = (float*)(ws + 64 * MB);            // 64MB, clobbers X (dead)
    ushort_t* Vt = (ushort_t*)(ws + 16 * MB);        // post-scores, over Ql

    // scores: per batch M=2048, N=2048, K'=3*1024, fp32 out
    gemm256<3, 0><<<dim3(8, 32), 512, 131072, stream>>>(
        Qh, Ql, Kh, Kl, Sbuf, nullptr, nullptr, nullptr,
        16, 1024, 1024, 2048, 8,
        (size_t)ATT_S * 1024, (size_t)ATT_S * 1024, (size_t)ATT_S * 2048);

    // V projection (1-term, fp32 A from input x), V^T out over dead Ql
    gemm_bt<1, 1, 2><<<dim3(8, 64), 256, 0, stream>>>(
        x, nullptr, Wvh, nullptr, Vt, nullptr,
        1024, 1024, 1024, 0, 64, 0, 0, 0);

    // softmax over all 8192 rows
    softmax_inplace<<<dim3(ATT_B * ATT_S / 4), 256, 0, stream>>>(Sbuf);

    // PV: per batch M=2048, N=1024, K=2048; A=P bf16 (pitch 4096)
    gemm_bt<1, 0, 0><<<dim3(8, 64), 256, 0, stream>>>(
        (const ushort_t*)Sbuf, nullptr, Vt, nullptr, out, nullptr,
        2048, 4096, 2048, 1024, 16,
        (size_t)ATT_S * 4096, (size_t)1024 * 2048, (size_t)ATT_S * 1024);
  } else {
    // ===== Tier C: two h=1024 stripes (ws >= 112MB) ========================
    const int h = 1024;
    float* Sbuf = (float*)(ws + 64 * MB);            // 32MB
    ushort_t* Vt = (ushort_t*)(ws + 96 * MB);        // 16MB

    // V projection first (Vt region untouched by scores)
    gemm_bt<1, 1, 2><<<dim3(8, 64), 256, 0, stream>>>(
        x, nullptr, Wvh, nullptr, Vt, nullptr,
        1024, 1024, 1024, 0, 64, 0, 0, 0);

    for (int p = 0; p < ATT_S / h; ++p) {
      gemm256<3, 0><<<dim3(8, ATT_B * h / 256), 512, 131072, stream>>>(
          Qh + (size_t)p * h * 1024, Ql + (size_t)p * h * 1024, Kh, Kl,
          Sbuf, nullptr, nullptr, nullptr,
          16, 1024, 1024, 2048, h / 256,
          (size_t)ATT_S * 1024, (size_t)ATT_S * 1024, (size_t)h * 2048);
      softmax_inplace<<<dim3(ATT_B * h / 4), 256, 0, stream>>>(Sbuf);
      gemm_bt<1, 0, 0><<<dim3(8, ATT_B * h / 128), 256, 0, stream>>>(
          (const ushort_t*)Sbuf, nullptr, Vt, nullptr,
          out + (size_t)p * h * 1024, nullptr,
          2048, 4096, 2048, 1024, h / 128,
          (size_t)h * 4096, (size_t)1024 * 2048, (size_t)ATT_S * 1024);
    }
  }
}

// Round 6
// 407.483 us; speedup vs baseline: 22.5467x; 1.0160x over previous
//
#include <hip/hip_runtime.h>
#include <hip/hip_bf16.h>

#define ATT_B 4
#define ATT_S 2048
#define ATT_D 1024

#define BM 128
#define BN 128
#define BK 32

typedef __attribute__((ext_vector_type(8))) short bf16x8;   // MFMA A/B frag (8 bf16)
typedef __attribute__((ext_vector_type(4))) float f32x4;    // MFMA C/D frag
typedef unsigned short ushort_t;

// round-to-nearest-even f32 -> bf16 bits
__device__ inline unsigned short f2bf_rne(float f) {
  unsigned u = __float_as_uint(f);
  u += 0x7FFFu + ((u >> 16) & 1u);
  return (unsigned short)(u >> 16);
}

// async global->LDS, 16B per lane. lds ptr must be wave-uniform.
__device__ inline void gll16(const void* g, void* l) {
  __builtin_amdgcn_global_load_lds(
      (const __attribute__((address_space(1))) void*)g,
      (__attribute__((address_space(3))) void*)l, 16, 0, 0);
}

// ===========================================================================
// 256x256 8-wave deep-pipelined GEMM (BK=64 per K-tile, 2 ksteps of 32).
// C[M,N] = A[M,K'] * B[N,K']^T with K' = NTERM*K0 via segment pointer cycle:
//   NTERM=3: A segs {hi,lo,hi}, B segs {hi,hi,lo}  (split-bf16 3-term product)
// OM=0: fp32 C (batched).  OM=1: hi/lo bf16 out, n<1024 -> (C0,C1), else (C2,C3).
// Counted-vmcnt schedule (T4): ONE vmcnt per K-tile at phase 3:
//   t < NT-2 -> vmcnt(4); t == NT-2 -> vmcnt(0); t == NT-1 -> none.
// NOTE (R4->R5): sched_barrier(0) removed from all phases — m141-class
// order-pinning; compiler-visible ds_reads carry their own precise waits.
// ===========================================================================
template<int NTERM, int OM>
__global__ __launch_bounds__(512, 2)
void gemm256(const ushort_t* __restrict__ Ah, const ushort_t* __restrict__ Al,
             const ushort_t* __restrict__ Bh, const ushort_t* __restrict__ Bl,
             void* __restrict__ C0, void* __restrict__ C1,
             void* __restrict__ C2, void* __restrict__ C3,
             int NT0, int pitchA, int pitchB, int pitchC, int mtiles_pb,
             size_t AbStride, size_t BbStride, size_t CbStride)
{
  extern __shared__ char lds[];   // 131072 bytes at launch
  const int tid  = threadIdx.x;
  const int wave = tid >> 6, lane = tid & 63;
  const int l16  = lane & 15, lh = lane >> 4;
  const int wm   = wave >> 2;          // 0..1  (M half)
  const int wn   = wave & 3;           // 0..3  (N quarter)

  // XCD-aware block swizzle (grids here always have nwg % 8 == 0)
  const int bid = blockIdx.x + gridDim.x * blockIdx.y;
  const int nwg = gridDim.x * gridDim.y;
  const int swz = (bid & 7) * (nwg >> 3) + (bid >> 3);
  const int bx  = swz % gridDim.x;
  const int by  = swz / gridDim.x;

  const int bt   = by / mtiles_pb;
  const int row0 = (by % mtiles_pb) * 256;
  const int col0 = bx * 256;

  const ushort_t* Ahb = Ah + (size_t)bt * AbStride;
  const ushort_t* Alb = (NTERM == 3) ? (Al + (size_t)bt * AbStride) : nullptr;
  const ushort_t* Bhb = Bh + (size_t)bt * BbStride;
  const ushort_t* Blb = (NTERM == 3) ? (Bl + (size_t)bt * BbStride) : nullptr;

  const int NT = NTERM * NT0;

  // segment resolver: tile t -> (A src, B src, k element offset)
  auto srcs = [&](int t, const ushort_t*& As, const ushort_t*& Bs, int& koff) {
    int seg = 0;
    if (NTERM == 3) seg = (t >= 2 * NT0) ? 2 : ((t >= NT0) ? 1 : 0);
    koff = (t - seg * NT0) * 64;
    As = (NTERM == 3 && seg == 1) ? Alb : Ahb;
    Bs = (NTERM == 3 && seg == 2) ? Blb : Bhb;
  };

  // stage one 16KB k-half (256 rows x 32 cols) into LDS; linear dest,
  // inverse-swizzled global source (rule #21).
  auto stage = [&](const ushort_t* src, int rowbase, int pitch, int koff,
                   int kh, int op, int p) {
#pragma unroll
    for (int c = 0; c < 2; ++c) {
      const int chunk = wave + c * 8;
      const int o  = chunk * 1024 + lane * 16;
      const int os = o ^ (((o >> 7) & 3) << 4);
      const int row  = os >> 6;
      const int colb = os & 63;
      const char* g = (const char*)src +
          ((size_t)(rowbase + row) * pitch + koff + kh * 32) * 2 + colb;
      gll16(g, lds + op * 65536 + p * 32768 + kh * 16384 + chunk * 1024);
    }
  };

  auto ldA = [&](int p, int ks, int row) -> bf16x8 {
    int local = row * 64 + lh * 16;
    local ^= ((local >> 7) & 3) << 4;
    return *(const bf16x8*)(lds + p * 32768 + ks * 16384 + local);
  };
  auto ldB = [&](int p, int ks, int row) -> bf16x8 {
    int local = row * 64 + lh * 16;
    local ^= ((local >> 7) & 3) << 4;
    return *(const bf16x8*)(lds + 65536 + p * 32768 + ks * 16384 + local);
  };

  f32x4 acc[8][4] = {};

  // ---- prologue: tile0 (both k-halves) -> buf0; tile1 k-half0 -> buf1 -----
  {
    const ushort_t *As, *Bs; int ko;
    srcs(0, As, Bs, ko);
    stage(As, row0, pitchA, ko, 0, 0, 0);
    stage(Bs, col0, pitchB, ko, 0, 1, 0);
    stage(As, row0, pitchA, ko, 1, 0, 0);
    stage(Bs, col0, pitchB, ko, 1, 1, 0);
    srcs(1, As, Bs, ko);
    stage(As, row0, pitchA, ko, 0, 0, 1);
    stage(Bs, col0, pitchB, ko, 0, 1, 1);
    asm volatile("s_waitcnt vmcnt(4)" ::: "memory");   // land ALL of tile 0
    __builtin_amdgcn_s_barrier();
  }

  auto mma16 = [&](bf16x8 (&a)[4], bf16x8 (&b)[4], int mh) {
    __builtin_amdgcn_s_setprio(1);
#pragma unroll
    for (int mf = 0; mf < 4; ++mf)
#pragma unroll
      for (int nf = 0; nf < 4; ++nf)
        acc[mh * 4 + mf][nf] = __builtin_amdgcn_mfma_f32_16x16x32_bf16(
            a[mf], b[nf], acc[mh * 4 + mf][nf], 0, 0, 0);
    __builtin_amdgcn_s_setprio(0);
  };

  // ---- main loop: 4 phases per K-tile, ONE counted vmcnt at phase 3 ------
  for (int t = 0; t < NT; ++t) {
    const int p = t & 1;
    const ushort_t *As1, *Bs1, *As2, *Bs2; int ko1, ko2;
    srcs(t + 1, As1, Bs1, ko1);
    srcs(t + 2, As2, Bs2, ko2);
    const bool st1 = (t + 1 < NT), st2 = (t + 2 < NT);

    bf16x8 a[4], b[4];

    // phase 0: ks=0 mh=0 | stage A-kh1(t+1) -> buf p^1
#pragma unroll
    for (int f = 0; f < 4; ++f) a[f] = ldA(p, 0, wm * 128 + f * 16 + l16);
#pragma unroll
    for (int f = 0; f < 4; ++f) b[f] = ldB(p, 0, wn * 64 + f * 16 + l16);
    if (st1) stage(As1, row0, pitchA, ko1, 1, 0, p ^ 1);
    __builtin_amdgcn_s_barrier();
    asm volatile("s_waitcnt lgkmcnt(0)" ::: "memory");
    mma16(a, b, 0);
    __builtin_amdgcn_s_barrier();

    // phase 1: ks=0 mh=1 (b reused) | stage B-kh1(t+1) -> buf p^1
#pragma unroll
    for (int f = 0; f < 4; ++f) a[f] = ldA(p, 0, wm * 128 + 64 + f * 16 + l16);
    if (st1) stage(Bs1, col0, pitchB, ko1, 1, 1, p ^ 1);
    __builtin_amdgcn_s_barrier();
    asm volatile("s_waitcnt lgkmcnt(0)" ::: "memory");
    mma16(a, b, 1);
    __builtin_amdgcn_s_barrier();

    // phase 2: ks=1 mh=0 | stage A-kh0(t+2) -> buf p
#pragma unroll
    for (int f = 0; f < 4; ++f) a[f] = ldA(p, 1, wm * 128 + f * 16 + l16);
#pragma unroll
    for (int f = 0; f < 4; ++f) b[f] = ldB(p, 1, wn * 64 + f * 16 + l16);
    if (st2) stage(As2, row0, pitchA, ko2, 0, 0, p);
    __builtin_amdgcn_s_barrier();
    asm volatile("s_waitcnt lgkmcnt(0)" ::: "memory");
    mma16(a, b, 0);
    __builtin_amdgcn_s_barrier();

    // phase 3: ks=1 mh=1 (b reused) | stage B-kh0(t+2) -> buf p | vmcnt
#pragma unroll
    for (int f = 0; f < 4; ++f) a[f] = ldA(p, 1, wm * 128 + 64 + f * 16 + l16);
    if (st2) stage(Bs2, col0, pitchB, ko2, 0, 1, p);
    if (t < NT - 2)       asm volatile("s_waitcnt vmcnt(4)" ::: "memory");
    else if (t == NT - 2) asm volatile("s_waitcnt vmcnt(0)" ::: "memory");
    __builtin_amdgcn_s_barrier();
    asm volatile("s_waitcnt lgkmcnt(0)" ::: "memory");
    mma16(a, b, 1);
    __builtin_amdgcn_s_barrier();
  }

  // ---- epilogue (m89-verified frag layout: row=(lh*4+r), col=l16) --------
#pragma unroll
  for (int i = 0; i < 8; ++i) {
    const int mBase = row0 + wm * 128 + (i >> 2) * 64 + (i & 3) * 16 + lh * 4;
#pragma unroll
    for (int nf = 0; nf < 4; ++nf) {
      const int n = col0 + wn * 64 + nf * 16 + l16;
      if (OM == 0) {
        float* Cb = (float*)C0 + (size_t)bt * CbStride;
#pragma unroll
        for (int r = 0; r < 4; ++r)
          Cb[(size_t)(mBase + r) * pitchC + n] = acc[i][nf][r];
      } else {
        ushort_t* Dh = (ushort_t*)((col0 < 1024) ? C0 : C2);
        ushort_t* Dl = (ushort_t*)((col0 < 1024) ? C1 : C3);
        const int nn = (col0 < 1024) ? n : (n - 1024);
#pragma unroll
        for (int r = 0; r < 4; ++r) {
          const float f = acc[i][nf][r];
          const unsigned u = __float_as_uint(f);
          Dh[(size_t)(mBase + r) * pitchC + nn] = (ushort_t)(u >> 16);
          Dl[(size_t)(mBase + r) * pitchC + nn] =
              f2bf_rne(f - __uint_as_float(u & 0xFFFF0000u));
        }
      }
    }
  }
}

// ===========================================================================
// Proven 128x128 GEMM (V-projection, PV).
// ===========================================================================
template<int NT, int AMODE, int OMODE>
__global__ __launch_bounds__(256, 2)
void gemm_bt(const void* __restrict__ Apv, const void* __restrict__ Alv,
             const ushort_t* __restrict__ Bh, const ushort_t* __restrict__ Bl,
             void* __restrict__ C0, void* __restrict__ C1,
             int K, int pitchA, int pitchB, int pitchC, int mtiles_pb,
             size_t Abstride, size_t Bbstride, size_t Cbstride)
{
  __shared__ ushort_t sAh[BM * BK];
  __shared__ ushort_t sBh[BN * BK];

  const int tid  = threadIdx.x;
  const int wave = tid >> 6;
  const int lane = tid & 63;
  const int l16  = lane & 15;
  const int lh   = lane >> 4;
  const int wm   = wave >> 1;
  const int wn   = wave & 1;

  const int bt   = blockIdx.y / mtiles_pb;
  const int ml   = blockIdx.y % mtiles_pb;
  const int row0 = ml * BM;
  const int col0 = blockIdx.x * BN;

  const ushort_t* Bhb = Bh + (size_t)bt * Bbstride;

  const ushort_t* Ahb = nullptr;
  const float*    Af  = nullptr;
  if (AMODE == 0) Ahb = (const ushort_t*)Apv + (size_t)bt * Abstride;
  else            Af  = (const float*)Apv + (size_t)bt * Abstride;

  f32x4 acc[4][4] = {};

  for (int k0 = 0; k0 < K; k0 += BK) {
#pragma unroll
    for (int j = 0; j < 2; ++j) {
      const int off = tid * 16 + j * 4096;
      const int r   = off >> 6;
      const int kb  = off & 63;
      const char* g = (const char*)Bhb + ((size_t)(col0 + r) * pitchB + k0) * 2 + kb;
      gll16(g, (char*)sBh + (wave << 10) + j * 4096);
    }
    if (AMODE == 0) {
#pragma unroll
      for (int j = 0; j < 2; ++j) {
        const int off = tid * 16 + j * 4096;
        const int r   = off >> 6;
        const int kb  = off & 63;
        const char* g = (const char*)Ahb + ((size_t)(row0 + r) * pitchA + k0) * 2 + kb;
        gll16(g, (char*)sAh + (wave << 10) + j * 4096);
      }
    } else {
#pragma unroll
      for (int j = 0; j < 4; ++j) {
        const int lin4 = tid + j * 256;
        const int r    = lin4 >> 3;
        const int c4   = lin4 & 7;
        const float4 v = *(const float4*)(Af + (size_t)(row0 + r) * pitchA + k0 + c4 * 4);
        ushort4 hi;
        hi.x = (ushort_t)(__float_as_uint(v.x) >> 16);
        hi.y = (ushort_t)(__float_as_uint(v.y) >> 16);
        hi.z = (ushort_t)(__float_as_uint(v.z) >> 16);
        hi.w = (ushort_t)(__float_as_uint(v.w) >> 16);
        *(ushort4*)&sAh[r * BK + c4 * 4] = hi;
      }
    }
    __syncthreads();

    bf16x8 ah[4], bh4[4];
#pragma unroll
    for (int t = 0; t < 4; ++t) {
      ah[t]  = *(const bf16x8*)&sAh[(wm * 64 + t * 16 + l16) * BK + lh * 8];
      bh4[t] = *(const bf16x8*)&sBh[(wn * 64 + t * 16 + l16) * BK + lh * 8];
    }
#pragma unroll
    for (int i = 0; i < 4; ++i)
#pragma unroll
      for (int j = 0; j < 4; ++j)
        acc[i][j] = __builtin_amdgcn_mfma_f32_16x16x32_bf16(ah[i], bh4[j], acc[i][j], 0, 0, 0);
    __syncthreads();
  }

#pragma unroll
  for (int i = 0; i < 4; ++i) {
    const int mBase = row0 + wm * 64 + i * 16 + lh * 4;
#pragma unroll
    for (int j = 0; j < 4; ++j) {
      const int n = col0 + wn * 64 + j * 16 + l16;
      if (OMODE == 0) {
        float* C = (float*)C0 + (size_t)bt * Cbstride;
#pragma unroll
        for (int r = 0; r < 4; ++r)
          C[(size_t)(mBase + r) * pitchC + n] = acc[i][j][r];
      } else {
        // V^T store: Vt[batch][n][srow]
        ushort_t* Vt = (ushort_t*)C0;
        const int b2 = mBase >> 11;
        const int sr = mBase & 2047;
        ushort4 o;
        o.x = f2bf_rne(acc[i][j][0]); o.y = f2bf_rne(acc[i][j][1]);
        o.z = f2bf_rne(acc[i][j][2]); o.w = f2bf_rne(acc[i][j][3]);
        *(ushort4*)&Vt[(size_t)b2 * (1024u * 2048u) + (size_t)n * 2048 + sr] = o;
      }
    }
  }
}

// ---------------------------------------------------------------------------
// W [1024][1024] fp32 -> Wh/Wl bf16 [n][k] (transposed, split); z picks W.
// ---------------------------------------------------------------------------
__global__ __launch_bounds__(256)
void wsplit3(const float* __restrict__ W0, const float* __restrict__ W1,
             const float* __restrict__ W2,
             ushort_t* __restrict__ H0, ushort_t* __restrict__ L0,
             ushort_t* __restrict__ H1, ushort_t* __restrict__ L1,
             ushort_t* __restrict__ H2, ushort_t* __restrict__ L2) {
  const float* W = (blockIdx.z == 0) ? W0 : (blockIdx.z == 1) ? W1 : W2;
  ushort_t* Wh   = (blockIdx.z == 0) ? H0 : (blockIdx.z == 1) ? H1 : H2;
  ushort_t* Wl   = (blockIdx.z == 0) ? L0 : (blockIdx.z == 1) ? L1 : L2;
  __shared__ float t[32][33];
  const int k0 = blockIdx.x * 32;
  const int n0 = blockIdx.y * 32;
  const int tx = threadIdx.x & 31;
  const int ty = threadIdx.x >> 5;
#pragma unroll
  for (int i = 0; i < 32; i += 8)
    t[ty + i][tx] = W[(size_t)(k0 + ty + i) * 1024 + (n0 + tx)];
  __syncthreads();
#pragma unroll
  for (int i = 0; i < 32; i += 8) {
    const float f = t[tx][ty + i];
    const unsigned u = __float_as_uint(f);
    Wh[(size_t)(n0 + ty + i) * 1024 + (k0 + tx)] = (ushort_t)(u >> 16);
    Wl[(size_t)(n0 + ty + i) * 1024 + (k0 + tx)] =
        f2bf_rne(f - __uint_as_float(u & 0xFFFF0000u));
  }
}

// ---------------------------------------------------------------------------
// x fp32 [8192*1024] -> Xh, Xl bf16
// ---------------------------------------------------------------------------
__global__ __launch_bounds__(256)
void xsplit(const float* __restrict__ x, ushort_t* __restrict__ Xh,
            ushort_t* __restrict__ Xl) {
  const size_t i0 = ((size_t)blockIdx.x * 256 + threadIdx.x) * 16;
#pragma unroll
  for (int j = 0; j < 4; ++j) {
    const float4 v = *(const float4*)(x + i0 + j * 4);
    const unsigned ux = __float_as_uint(v.x), uy = __float_as_uint(v.y);
    const unsigned uz = __float_as_uint(v.z), uw = __float_as_uint(v.w);
    ushort4 hi, lo;
    hi.x = (ushort_t)(ux >> 16); hi.y = (ushort_t)(uy >> 16);
    hi.z = (ushort_t)(uz >> 16); hi.w = (ushort_t)(uw >> 16);
    lo.x = f2bf_rne(v.x - __uint_as_float(ux & 0xFFFF0000u));
    lo.y = f2bf_rne(v.y - __uint_as_float(uy & 0xFFFF0000u));
    lo.z = f2bf_rne(v.z - __uint_as_float(uz & 0xFFFF0000u));
    lo.w = f2bf_rne(v.w - __uint_as_float(uw & 0xFFFF0000u));
    *(ushort4*)(Xh + i0 + j * 4) = hi;
    *(ushort4*)(Xl + i0 + j * 4) = lo;
  }
}

// ---------------------------------------------------------------------------
// Row softmax in place: 2048 fp32 scores -> 2048 bf16 P (start of same row).
// ---------------------------------------------------------------------------
__global__ __launch_bounds__(256)
void softmax_inplace(float* __restrict__ S) {
  const int wave = threadIdx.x >> 6;
  const int lane = threadIdx.x & 63;
  float* rp = S + ((size_t)blockIdx.x * 4 + wave) * 2048;

  float4 v[8];
#pragma unroll
  for (int i = 0; i < 8; ++i) v[i] = *(const float4*)&rp[lane * 4 + i * 256];

  float m = -1e30f;
#pragma unroll
  for (int i = 0; i < 8; ++i)
    m = fmaxf(m, fmaxf(fmaxf(v[i].x, v[i].y), fmaxf(v[i].z, v[i].w)));
#pragma unroll
  for (int s = 32; s; s >>= 1) m = fmaxf(m, __shfl_xor(m, s));

  float sum = 0.f;
#pragma unroll
  for (int i = 0; i < 8; ++i) {
    v[i].x = __expf(v[i].x - m); v[i].y = __expf(v[i].y - m);
    v[i].z = __expf(v[i].z - m); v[i].w = __expf(v[i].w - m);
    sum += (v[i].x + v[i].y) + (v[i].z + v[i].w);
  }
#pragma unroll
  for (int s = 32; s; s >>= 1) sum += __shfl_xor(sum, s);
  const float inv = 1.0f / sum;

  ushort_t* pp = (ushort_t*)rp;
#pragma unroll
  for (int i = 0; i < 8; ++i) {
    ushort4 o;
    o.x = f2bf_rne(v[i].x * inv); o.y = f2bf_rne(v[i].y * inv);
    o.z = f2bf_rne(v[i].z * inv); o.w = f2bf_rne(v[i].w * inv);
    *(ushort4*)&pp[lane * 4 + i * 256] = o;
  }
}

// ---------------------------------------------------------------------------
extern "C" void kernel_launch(void* const* d_in, const int* in_sizes, int n_in,
                              void* d_out, int out_size, void* d_ws, size_t ws_size,
                              hipStream_t stream) {
  const float* x  = (const float*)d_in[0];
  const float* Wq = (const float*)d_in[1];
  const float* Wk = (const float*)d_in[2];
  const float* Wv = (const float*)d_in[3];
  float* out = (float*)d_out;

  char* ws = (char*)d_ws;
  char* ob = (char*)d_out;
  const size_t MB = 1024 * 1024;

  // persistent QK (hi/lo): [0,64) MB
  ushort_t* Qh = (ushort_t*)(ws +  0 * MB);
  ushort_t* Ql = (ushort_t*)(ws + 16 * MB);
  ushort_t* Kh = (ushort_t*)(ws + 32 * MB);
  ushort_t* Kl = (ushort_t*)(ws + 48 * MB);
  // transient X (dead once scores run): [64,96) MB
  ushort_t* Xh = (ushort_t*)(ws + 64 * MB);
  ushort_t* Xl = (ushort_t*)(ws + 80 * MB);
  // W slabs live in d_out (dead before PV, which fully rewrites d_out)
  ushort_t* Wqkh = (ushort_t*)(ob + 0 * MB);   // 4MB: Wq^T hi | Wk^T hi
  ushort_t* Wqkl = (ushort_t*)(ob + 4 * MB);   // 4MB
  ushort_t* Wvh  = (ushort_t*)(ob + 8 * MB);   // 2MB
  ushort_t* Wvl  = (ushort_t*)(ob + 10 * MB);  // 2MB (unused after split)

  // ---- shared preprocessing ----------------------------------------------
  wsplit3<<<dim3(32, 32, 3), 256, 0, stream>>>(
      Wq, Wk, Wv, Wqkh, Wqkl, Wqkh + 1024 * 1024, Wqkl + 1024 * 1024, Wvh, Wvl);
  xsplit<<<2048, 256, 0, stream>>>(x, Xh, Xl);

  // ---- fused Q+K projection: M=8192, N=2048, K'=3*1024 --------------------
  gemm256<3, 1><<<dim3(8, 32), 512, 131072, stream>>>(
      Xh, Xl, Wqkh, Wqkl, Qh, Ql, Kh, Kl,
      16, 1024, 1024, 1024, 32, 0, 0, 0);

  if (ws_size >= 128 * MB) {
    // ===== Tier B': single-dispatch full-S scores (256 wg) =================
    float* Sbuf = (float*)(ws + 64 * MB);            // 64MB, clobbers X (dead)
    ushort_t* Vt = (ushort_t*)(ws + 16 * MB);        // post-scores, over Ql

    // scores: per batch M=2048, N=2048, K'=3*1024, fp32 out
    gemm256<3, 0><<<dim3(8, 32), 512, 131072, stream>>>(
        Qh, Ql, Kh, Kl, Sbuf, nullptr, nullptr, nullptr,
        16, 1024, 1024, 2048, 8,
        (size_t)ATT_S * 1024, (size_t)ATT_S * 1024, (size_t)ATT_S * 2048);

    // V projection (1-term, fp32 A from input x), V^T out over dead Ql
    gemm_bt<1, 1, 2><<<dim3(8, 64), 256, 0, stream>>>(
        x, nullptr, Wvh, nullptr, Vt, nullptr,
        1024, 1024, 1024, 0, 64, 0, 0, 0);

    // softmax over all 8192 rows
    softmax_inplace<<<dim3(ATT_B * ATT_S / 4), 256, 0, stream>>>(Sbuf);

    // PV: per batch M=2048, N=1024, K=2048; A=P bf16 (pitch 4096)
    gemm_bt<1, 0, 0><<<dim3(8, 64), 256, 0, stream>>>(
        (const ushort_t*)Sbuf, nullptr, Vt, nullptr, out, nullptr,
        2048, 4096, 2048, 1024, 16,
        (size_t)ATT_S * 4096, (size_t)1024 * 2048, (size_t)ATT_S * 1024);
  } else {
    // ===== Tier C: two h=1024 stripes (ws >= 112MB) ========================
    const int h = 1024;
    float* Sbuf = (float*)(ws + 64 * MB);            // 32MB
    ushort_t* Vt = (ushort_t*)(ws + 96 * MB);        // 16MB

    // V projection first (Vt region untouched by scores)
    gemm_bt<1, 1, 2><<<dim3(8, 64), 256, 0, stream>>>(
        x, nullptr, Wvh, nullptr, Vt, nullptr,
        1024, 1024, 1024, 0, 64, 0, 0, 0);

    for (int p = 0; p < ATT_S / h; ++p) {
      gemm256<3, 0><<<dim3(8, ATT_B * h / 256), 512, 131072, stream>>>(
          Qh + (size_t)p * h * 1024, Ql + (size_t)p * h * 1024, Kh, Kl,
          Sbuf, nullptr, nullptr, nullptr,
          16, 1024, 1024, 2048, h / 256,
          (size_t)ATT_S * 1024, (size_t)ATT_S * 1024, (size_t)h * 2048);
      softmax_inplace<<<dim3(ATT_B * h / 4), 256, 0, stream>>>(Sbuf);
      gemm_bt<1, 0, 0><<<dim3(8, ATT_B * h / 128), 256, 0, stream>>>(
          (const ushort_t*)Sbuf, nullptr, Vt, nullptr,
          out + (size_t)p * h * 1024, nullptr,
          2048, 4096, 2048, 1024, h / 128,
          (size_t)h * 4096, (size_t)1024 * 2048, (size_t)ATT_S * 1024);
    }
  }
}